// Round 1
// baseline (825.381 us; speedup 1.0000x reference)
//
#include <hip/hip_runtime.h>
#include <math.h>

#define NB 128          // batch of graphs
#define E_PER 2048
#define NE (NB * E_PER) // 262144 edges
#define FD 128          // feature dim (F_IN = NHID)

// ---------------- GEMM: C[N x 128] = A[N x 128] @ W[128 x 128] (f32) ----------
__global__ __launch_bounds__(256) void gemm128(const float* __restrict__ A,
                                               const float* __restrict__ W,
                                               float* __restrict__ C) {
    __shared__ float Wl[128 * 128];   // 64 KB
    __shared__ float Atl[128 * 36];   // transposed A tile, padded (18 KB)
    const int tid = threadIdx.x;
    const long rbase = (long)blockIdx.x * 32;

    for (int i = tid; i < 4096; i += 256)
        ((float4*)Wl)[i] = ((const float4*)W)[i];
    for (int i = tid; i < 1024; i += 256) {
        int row = i >> 5, kq = i & 31;
        float4 a = *(const float4*)&A[(rbase + row) * FD + kq * 4];
        Atl[(kq * 4 + 0) * 36 + row] = a.x;
        Atl[(kq * 4 + 1) * 36 + row] = a.y;
        Atl[(kq * 4 + 2) * 36 + row] = a.z;
        Atl[(kq * 4 + 3) * 36 + row] = a.w;
    }
    __syncthreads();

    const int cq = tid & 31, rq = tid >> 5;   // 32 col-quads x 8 row-quads
    float acc[4][4];
#pragma unroll
    for (int i = 0; i < 4; ++i)
#pragma unroll
        for (int j = 0; j < 4; ++j) acc[i][j] = 0.f;

#pragma unroll 4
    for (int k = 0; k < 128; ++k) {
        float4 a = *(const float4*)&Atl[k * 36 + rq * 4];
        float4 b = *(const float4*)&Wl[k * 128 + cq * 4];
        float av[4] = {a.x, a.y, a.z, a.w};
        float bv[4] = {b.x, b.y, b.z, b.w};
#pragma unroll
        for (int i = 0; i < 4; ++i)
#pragma unroll
            for (int j = 0; j < 4; ++j) acc[i][j] += av[i] * bv[j];
    }
#pragma unroll
    for (int ri = 0; ri < 4; ++ri) {
        float4 o = {acc[ri][0], acc[ri][1], acc[ri][2], acc[ri][3]};
        *(float4*)&C[(rbase + rq * 4 + ri) * FD + cq * 4] = o;
    }
}

// ---------------- degree -> dinv = 1/sqrt(1 + sum(ew into dst)) ----------------
__global__ __launch_bounds__(256) void deg_kernel(const int* __restrict__ dst,
                                                  const float* __restrict__ ew,
                                                  int n_per, float* __restrict__ dinv) {
    __shared__ float cnt[512];
    const int g = blockIdx.x, tid = threadIdx.x;
    for (int i = tid; i < n_per; i += 256) cnt[i] = 0.f;
    __syncthreads();
    const int ebase = g * E_PER;
    for (int i = tid; i < E_PER; i += 256) {
        float w = ew ? ew[ebase + i] : 1.0f;
        if (w != 0.f) atomicAdd(&cnt[dst[ebase + i] - g * n_per], w);
    }
    __syncthreads();
    for (int i = tid; i < n_per; i += 256)
        dinv[g * n_per + i] = 1.0f / sqrtf(1.0f + cnt[i]);
}

// ------------- aggregate: hout = relu(scatter(msg) + hpre*dinv^2 + b) ----------
#define FCHUNK 32
__global__ __launch_bounds__(256) void agg_kernel(const float* __restrict__ hpre,
                                                  const int* __restrict__ src,
                                                  const int* __restrict__ dst,
                                                  const float* __restrict__ ew,
                                                  const float* __restrict__ dinv,
                                                  const float* __restrict__ bias,
                                                  int n_per, float* __restrict__ hout) {
    __shared__ float acc[512 * FCHUNK];  // 64 KB
    __shared__ float dl[512];
    const int tid = threadIdx.x;
    const int g = blockIdx.x >> 2;
    const int fc = (blockIdx.x & 3) * FCHUNK;
    const int nbase = g * n_per;
    for (int i = tid; i < n_per * FCHUNK; i += 256) acc[i] = 0.f;
    for (int i = tid; i < n_per; i += 256) dl[i] = dinv[nbase + i];
    __syncthreads();
    const int lane = tid & 63;
    const int sub = lane >> 5;      // which of 2 edges this half-wave handles
    const int fl = lane & 31;
    const int wv = tid >> 6;
    const int f = fc + fl;
    for (int eo = wv * 2 + sub; eo < E_PER; eo += 8) {
        const int e = g * E_PER + eo;
        float w = ew ? ew[e] : 1.0f;
        if (w != 0.f) {
            int s = src[e], d = dst[e];
            int slo = s - nbase, dlo = d - nbase;
            float coef = dl[slo] * dl[dlo] * w;
            float v = hpre[(long)s * FD + f] * coef;
            atomicAdd(&acc[dlo * FCHUNK + fl], v);
        }
    }
    __syncthreads();
    for (int i = tid; i < n_per * FCHUNK; i += 256) {
        int nl = i >> 5;
        int ff = fc + (i & 31);
        long n = nbase + nl;
        float di = dl[nl];
        float v = acc[i] + hpre[n * FD + ff] * di * di + bias[ff];
        hout[n * FD + ff] = fmaxf(v, 0.f);
    }
}

// ---------------- TopK pool: score, sort, gather*tanh, newid -------------------
__global__ __launch_bounds__(256) void pool_kernel(const float* __restrict__ h,
                                                   const float* __restrict__ p,
                                                   int n_per, int k,
                                                   float* __restrict__ xp,
                                                   int* __restrict__ newid) {
    __shared__ float sc[512];
    __shared__ int   sid[512];
    __shared__ float tf[256];
    __shared__ float pl[128];
    __shared__ float red[256];
    const int tid = threadIdx.x;
    const int g = blockIdx.x;
    const int nbase = g * n_per;

    float v = 0.f;
    if (tid < 128) { float pv = p[tid]; pl[tid] = pv; v = pv * pv; }
    red[tid] = v;
    __syncthreads();
    for (int s = 128; s > 0; s >>= 1) {
        if (tid < s) red[tid] += red[tid + s];
        __syncthreads();
    }
    const float invn = 1.0f / sqrtf(red[0]);

    for (int i = tid; i < n_per; i += 256) {
        const float4* hp = (const float4*)&h[(long)(nbase + i) * FD];
        const float4* pp = (const float4*)pl;
        float a = 0.f;
#pragma unroll
        for (int q = 0; q < 32; ++q) {
            float4 hv = hp[q], pv = pp[q];
            a += hv.x * pv.x + hv.y * pv.y + hv.z * pv.z + hv.w * pv.w;
        }
        sc[i] = a * invn;
        sid[i] = i;
    }
    // bitonic sort: descending score, ties -> lower index first
    for (int ksz = 2; ksz <= n_per; ksz <<= 1)
        for (int j = ksz >> 1; j > 0; j >>= 1) {
            __syncthreads();
            for (int i = tid; i < n_per; i += 256) {
                int l = i ^ j;
                if (l > i) {
                    float si = sc[i], slv = sc[l];
                    int ii = sid[i], il = sid[l];
                    bool up = ((i & ksz) == 0);
                    bool before = (si > slv) || (si == slv && ii < il);
                    if (up != before) { sc[i] = slv; sc[l] = si; sid[i] = il; sid[l] = ii; }
                }
            }
        }
    __syncthreads();
    for (int i = tid; i < n_per; i += 256) newid[nbase + i] = -1;
    __syncthreads();
    for (int r = tid; r < k; r += 256) {
        newid[nbase + sid[r]] = g * k + r;
        tf[r] = tanhf(sc[r]);
    }
    __syncthreads();
    for (int t = tid; t < k * FD; t += 256) {
        int r = t >> 7, f = t & 127;
        xp[((long)g * k + r) * FD + f] = h[(long)(nbase + sid[r]) * FD + f] * tf[r];
    }
}

// ---------------- edge relabel + mask ------------------------------------------
__global__ __launch_bounds__(256) void relabel_kernel(const int* __restrict__ src,
                                                      const int* __restrict__ dst,
                                                      const float* __restrict__ ew,
                                                      const int* __restrict__ newid,
                                                      int* __restrict__ nsrc,
                                                      int* __restrict__ ndst,
                                                      float* __restrict__ new_ew) {
    const int e = blockIdx.x * 256 + threadIdx.x;
    int s = src[e], d = dst[e];
    float w = ew ? ew[e] : 1.0f;
    int ns = newid[s], nd = newid[d];
    bool keep = (ns >= 0) && (nd >= 0);
    nsrc[e] = ns > 0 ? ns : 0;
    ndst[e] = nd > 0 ? nd : 0;
    new_ew[e] = keep ? w : 0.f;
}

// ---------------- readout: [max || mean] per graph -----------------------------
__global__ __launch_bounds__(128) void readout_kernel(const float* __restrict__ xp, int k,
                                                      float* __restrict__ r) {
    const int g = blockIdx.x, f = threadIdx.x;
    const float* base = xp + (long)g * k * FD;
    float mx = -INFINITY, sm = 0.f;
    for (int rr = 0; rr < k; ++rr) {
        float v = base[rr * FD + f];
        mx = fmaxf(mx, v);
        sm += v;
    }
    r[g * 256 + f] = mx;
    r[g * 256 + 128 + f] = sm / (float)k;
}

// ---------------- final MLP + log_softmax --------------------------------------
__global__ __launch_bounds__(128) void mlp_kernel(const float* __restrict__ r1,
                                                  const float* __restrict__ r2,
                                                  const float* __restrict__ r3,
                                                  const float* __restrict__ L1,
                                                  const float* __restrict__ bl1,
                                                  const float* __restrict__ L2,
                                                  const float* __restrict__ bl2,
                                                  const float* __restrict__ L3,
                                                  const float* __restrict__ bl3,
                                                  float* __restrict__ out) {
    __shared__ float z[256], z1[128], z2[64];
    const int g = blockIdx.x, tid = threadIdx.x;
    for (int t = tid; t < 256; t += 128)
        z[t] = r1[g * 256 + t] + r2[g * 256 + t] + r3[g * 256 + t];
    __syncthreads();
    {
        float a = bl1[tid];
        for (int i = 0; i < 256; ++i) a += z[i] * L1[i * 128 + tid];
        z1[tid] = fmaxf(a, 0.f);
    }
    __syncthreads();
    if (tid < 64) {
        float a = bl2[tid];
        for (int i = 0; i < 128; ++i) a += z1[i] * L2[i * 64 + tid];
        z2[tid] = fmaxf(a, 0.f);
    }
    __syncthreads();
    if (tid == 0) {
        float l0 = bl3[0], l1v = bl3[1];
        for (int i = 0; i < 64; ++i) {
            l0  += z2[i] * L3[i * 2 + 0];
            l1v += z2[i] * L3[i * 2 + 1];
        }
        float m = fmaxf(l0, l1v);
        float lse = m + logf(expf(l0 - m) + expf(l1v - m));
        out[g * 2 + 0] = l0 - lse;
        out[g * 2 + 1] = l1v - lse;
    }
}

extern "C" void kernel_launch(void* const* d_in, const int* in_sizes, int n_in,
                              void* d_out, int out_size, void* d_ws, size_t ws_size,
                              hipStream_t stream) {
    const float* x   = (const float*)d_in[0];
    const int*  src0 = (const int*)d_in[1];
    const int*  dst0 = (const int*)d_in[2];
    const float* W1 = (const float*)d_in[3];  const float* b1  = (const float*)d_in[4];
    const float* W2 = (const float*)d_in[5];  const float* b2  = (const float*)d_in[6];
    const float* W3 = (const float*)d_in[7];  const float* b3  = (const float*)d_in[8];
    const float* p1 = (const float*)d_in[9];  const float* p2  = (const float*)d_in[10];
    const float* p3 = (const float*)d_in[11];
    const float* L1 = (const float*)d_in[12]; const float* bl1 = (const float*)d_in[13];
    const float* L2 = (const float*)d_in[14]; const float* bl2 = (const float*)d_in[15];
    const float* L3 = (const float*)d_in[16]; const float* bl3 = (const float*)d_in[17];
    float* out = (float*)d_out;

    char* wptr = (char*)d_ws;
    auto alloc = [&](size_t bytes) {
        char* r = wptr;
        wptr += (bytes + 255) & ~(size_t)255;
        return r;
    };
    float* hpre = (float*)alloc(65536ULL * FD * 4);
    float* hbuf = (float*)alloc(65536ULL * FD * 4);
    float* xp2  = (float*)alloc(32768ULL * FD * 4);
    float* xp3  = (float*)alloc(16384ULL * FD * 4);
    float* xp4  = (float*)alloc(8192ULL * FD * 4);
    float* dinv = (float*)alloc(65536ULL * 4);
    int*   nid  = (int*)alloc(65536ULL * 4);
    int*   src1 = (int*)alloc(NE * 4);
    int*   dst1 = (int*)alloc(NE * 4);
    float* ew1  = (float*)alloc(NE * 4);
    int*   src2 = (int*)alloc(NE * 4);
    int*   dst2 = (int*)alloc(NE * 4);
    float* ew2  = (float*)alloc(NE * 4);
    float* r1   = (float*)alloc(128ULL * 256 * 4);
    float* r2   = (float*)alloc(128ULL * 256 * 4);
    float* r3   = (float*)alloc(128ULL * 256 * 4);

    // ---- stage 1 (n_per=512 -> k=256) ----
    gemm128<<<2048, 256, 0, stream>>>(x, W1, hpre);
    deg_kernel<<<NB, 256, 0, stream>>>(dst0, nullptr, 512, dinv);
    agg_kernel<<<NB * 4, 256, 0, stream>>>(hpre, src0, dst0, nullptr, dinv, b1, 512, hbuf);
    pool_kernel<<<NB, 256, 0, stream>>>(hbuf, p1, 512, 256, xp2, nid);
    relabel_kernel<<<NE / 256, 256, 0, stream>>>(src0, dst0, nullptr, nid, src1, dst1, ew1);
    readout_kernel<<<NB, 128, 0, stream>>>(xp2, 256, r1);

    // ---- stage 2 (n_per=256 -> k=128) ----
    gemm128<<<1024, 256, 0, stream>>>(xp2, W2, hpre);
    deg_kernel<<<NB, 256, 0, stream>>>(dst1, ew1, 256, dinv);
    agg_kernel<<<NB * 4, 256, 0, stream>>>(hpre, src1, dst1, ew1, dinv, b2, 256, hbuf);
    pool_kernel<<<NB, 256, 0, stream>>>(hbuf, p2, 256, 128, xp3, nid);
    relabel_kernel<<<NE / 256, 256, 0, stream>>>(src1, dst1, ew1, nid, src2, dst2, ew2);
    readout_kernel<<<NB, 128, 0, stream>>>(xp3, 128, r2);

    // ---- stage 3 (n_per=128 -> k=64) ----
    gemm128<<<512, 256, 0, stream>>>(xp3, W3, hpre);
    deg_kernel<<<NB, 256, 0, stream>>>(dst2, ew2, 128, dinv);
    agg_kernel<<<NB * 4, 256, 0, stream>>>(hpre, src2, dst2, ew2, dinv, b3, 128, hbuf);
    pool_kernel<<<NB, 256, 0, stream>>>(hbuf, p3, 128, 64, xp4, nid);
    readout_kernel<<<NB, 128, 0, stream>>>(xp4, 64, r3);

    // ---- final MLP ----
    mlp_kernel<<<NB, 128, 0, stream>>>(r1, r2, r3, L1, bl1, L2, bl2, L3, bl3, out);
}

// Round 4
// 559.268 us; speedup vs baseline: 1.4758x; 1.4758x over previous
//
#include <hip/hip_runtime.h>
#include <math.h>

#define NB 128          // batch of graphs
#define E_PER 2048
#define NE (NB * E_PER) // 262144 edges
#define FD 128          // feature dim (F_IN = NHID)

// ---------------- GEMM: C[N x 128] = A[N x 128] @ W[128 x 128] (f32) ----------
__global__ __launch_bounds__(256) void gemm128(const float* __restrict__ A,
                                               const float* __restrict__ W,
                                               float* __restrict__ C) {
    __shared__ float Wl[128 * 128];   // 64 KB
    __shared__ float Atl[128 * 36];   // transposed A tile, padded (18 KB)
    const int tid = threadIdx.x;
    const long rbase = (long)blockIdx.x * 32;

    for (int i = tid; i < 4096; i += 256)
        ((float4*)Wl)[i] = ((const float4*)W)[i];
    for (int i = tid; i < 1024; i += 256) {
        int row = i >> 5, kq = i & 31;
        float4 a = *(const float4*)&A[(rbase + row) * FD + kq * 4];
        Atl[(kq * 4 + 0) * 36 + row] = a.x;
        Atl[(kq * 4 + 1) * 36 + row] = a.y;
        Atl[(kq * 4 + 2) * 36 + row] = a.z;
        Atl[(kq * 4 + 3) * 36 + row] = a.w;
    }
    __syncthreads();

    const int cq = tid & 31, rq = tid >> 5;   // 32 col-quads x 8 row-quads
    float acc[4][4];
#pragma unroll
    for (int i = 0; i < 4; ++i)
#pragma unroll
        for (int j = 0; j < 4; ++j) acc[i][j] = 0.f;

#pragma unroll 4
    for (int k = 0; k < 128; ++k) {
        float4 a = *(const float4*)&Atl[k * 36 + rq * 4];
        float4 b = *(const float4*)&Wl[k * 128 + cq * 4];
        float av[4] = {a.x, a.y, a.z, a.w};
        float bv[4] = {b.x, b.y, b.z, b.w};
#pragma unroll
        for (int i = 0; i < 4; ++i)
#pragma unroll
            for (int j = 0; j < 4; ++j) acc[i][j] += av[i] * bv[j];
    }
#pragma unroll
    for (int ri = 0; ri < 4; ++ri) {
        float4 o = {acc[ri][0], acc[ri][1], acc[ri][2], acc[ri][3]};
        *(float4*)&C[(rbase + rq * 4 + ri) * FD + cq * 4] = o;
    }
}

// -------- build per-graph CSR by dst + dinv + edge coefficients ---------------
// one block per graph
__global__ __launch_bounds__(256) void build_csr(const int* __restrict__ src,
                                                 const int* __restrict__ dst,
                                                 const float* __restrict__ ew,
                                                 int n_per,
                                                 float* __restrict__ dinv,
                                                 int* __restrict__ roff,
                                                 int* __restrict__ csrc,
                                                 float* __restrict__ ccoef) {
    __shared__ int   cnt[512];
    __shared__ int   offs[513];
    __shared__ float dl[512];
    const int g = blockIdx.x, tid = threadIdx.x;
    const int ebase = g * E_PER;
    const int nbase = g * n_per;

    for (int i = tid; i < n_per; i += 256) cnt[i] = 0;
    __syncthreads();
    for (int i = tid; i < E_PER; i += 256) {
        float w = ew ? ew[ebase + i] : 1.0f;
        if (w != 0.f) atomicAdd(&cnt[dst[ebase + i] - nbase], 1);
    }
    __syncthreads();
    for (int i = tid; i < n_per; i += 256) {
        float di = rsqrtf(1.0f + (float)cnt[i]);
        dl[i] = di;
        dinv[nbase + i] = di;
    }
    // exclusive scan: serial on thread 0 (correct; cost is negligible at 128 blocks)
    __syncthreads();
    if (tid == 0) {
        int run = 0;
        for (int i = 0; i < n_per; ++i) { offs[i] = run; run += cnt[i]; }
        offs[n_per] = run;
    }
    __syncthreads();
    for (int i = tid; i <= n_per; i += 256)
        roff[g * (n_per + 1) + i] = ebase + offs[i];
    for (int i = tid; i < n_per; i += 256) cnt[i] = offs[i];  // cursors
    __syncthreads();
    for (int i = tid; i < E_PER; i += 256) {
        float w = ew ? ew[ebase + i] : 1.0f;
        if (w != 0.f) {
            int s = src[ebase + i], d = dst[ebase + i];
            int dlo = d - nbase;
            int pos = atomicAdd(&cnt[dlo], 1);
            csrc[ebase + pos]  = s;
            ccoef[ebase + pos] = dl[s - nbase] * dl[dlo] * w;
        }
    }
}

// -------- aggregate via CSR gather: hout = relu(sum + self + bias) ------------
// 2 nodes per block, 128 feature lanes per node
__global__ __launch_bounds__(256) void agg_csr(const float* __restrict__ hpre,
                                               const int* __restrict__ roff,
                                               const int* __restrict__ csrc,
                                               const float* __restrict__ ccoef,
                                               const float* __restrict__ dinv,
                                               const float* __restrict__ bias,
                                               int np_shift,
                                               float* __restrict__ hout) {
    const int tid = threadIdx.x;
    const int node = blockIdx.x * 2 + (tid >> 7);
    const int f = tid & 127;
    const int n_per = 1 << np_shift;
    const int g = node >> np_shift;
    const int nl = node & (n_per - 1);
    const int rbase = g * (n_per + 1) + nl;
    const int e0 = roff[rbase], e1 = roff[rbase + 1];
    float acc = 0.f;
    for (int e = e0; e < e1; ++e)
        acc += hpre[(long)csrc[e] * FD + f] * ccoef[e];
    const float di = dinv[node];
    float v = acc + hpre[(long)node * FD + f] * di * di + bias[f];
    hout[(long)node * FD + f] = fmaxf(v, 0.f);
}

// ---------------- TopK pool: score, sort, gather*tanh, newid -------------------
__global__ __launch_bounds__(256) void pool_kernel(const float* __restrict__ h,
                                                   const float* __restrict__ p,
                                                   int n_per, int k,
                                                   float* __restrict__ xp,
                                                   int* __restrict__ newid) {
    __shared__ float sc[512];
    __shared__ int   sid[512];
    __shared__ float tf[256];
    __shared__ float pl[128];
    __shared__ float red[256];
    const int tid = threadIdx.x;
    const int g = blockIdx.x;
    const int nbase = g * n_per;

    float v = 0.f;
    if (tid < 128) { float pv = p[tid]; pl[tid] = pv; v = pv * pv; }
    red[tid] = v;
    __syncthreads();
    for (int s = 128; s > 0; s >>= 1) {
        if (tid < s) red[tid] += red[tid + s];
        __syncthreads();
    }
    const float invn = 1.0f / sqrtf(red[0]);

    for (int i = tid; i < n_per; i += 256) {
        const float4* hp = (const float4*)&h[(long)(nbase + i) * FD];
        const float4* pp = (const float4*)pl;
        float a = 0.f;
#pragma unroll
        for (int q = 0; q < 32; ++q) {
            float4 hv = hp[q], pv = pp[q];
            a += hv.x * pv.x + hv.y * pv.y + hv.z * pv.z + hv.w * pv.w;
        }
        sc[i] = a * invn;
        sid[i] = i;
    }
    // bitonic sort: descending score, ties -> lower index first
    for (int ksz = 2; ksz <= n_per; ksz <<= 1)
        for (int j = ksz >> 1; j > 0; j >>= 1) {
            __syncthreads();
            for (int i = tid; i < n_per; i += 256) {
                int l = i ^ j;
                if (l > i) {
                    float si = sc[i], slv = sc[l];
                    int ii = sid[i], il = sid[l];
                    bool up = ((i & ksz) == 0);
                    bool before = (si > slv) || (si == slv && ii < il);
                    if (up != before) { sc[i] = slv; sc[l] = si; sid[i] = il; sid[l] = ii; }
                }
            }
        }
    __syncthreads();
    for (int i = tid; i < n_per; i += 256) newid[nbase + i] = -1;
    __syncthreads();
    for (int r = tid; r < k; r += 256) {
        newid[nbase + sid[r]] = g * k + r;
        tf[r] = tanhf(sc[r]);
    }
    __syncthreads();
    for (int t = tid; t < k * FD; t += 256) {
        int r = t >> 7, f = t & 127;
        xp[((long)g * k + r) * FD + f] = h[(long)(nbase + sid[r]) * FD + f] * tf[r];
    }
}

// ---------------- edge relabel + mask ------------------------------------------
__global__ __launch_bounds__(256) void relabel_kernel(const int* __restrict__ src,
                                                      const int* __restrict__ dst,
                                                      const float* __restrict__ ew,
                                                      const int* __restrict__ newid,
                                                      int* __restrict__ nsrc,
                                                      int* __restrict__ ndst,
                                                      float* __restrict__ new_ew) {
    const int e = blockIdx.x * 256 + threadIdx.x;
    int s = src[e], d = dst[e];
    float w = ew ? ew[e] : 1.0f;
    int ns = newid[s], nd = newid[d];
    bool keep = (ns >= 0) && (nd >= 0);
    nsrc[e] = ns > 0 ? ns : 0;
    ndst[e] = nd > 0 ? nd : 0;
    new_ew[e] = keep ? w : 0.f;
}

// ---------------- readout: [max || mean] per graph -----------------------------
__global__ __launch_bounds__(128) void readout_kernel(const float* __restrict__ xp, int k,
                                                      float* __restrict__ r) {
    const int g = blockIdx.x, f = threadIdx.x;
    const float* base = xp + (long)g * k * FD;
    float mx = -INFINITY, sm = 0.f;
    for (int rr = 0; rr < k; ++rr) {
        float v = base[rr * FD + f];
        mx = fmaxf(mx, v);
        sm += v;
    }
    r[g * 256 + f] = mx;
    r[g * 256 + 128 + f] = sm / (float)k;
}

// ---------------- final MLP + log_softmax --------------------------------------
__global__ __launch_bounds__(128) void mlp_kernel(const float* __restrict__ r1,
                                                  const float* __restrict__ r2,
                                                  const float* __restrict__ r3,
                                                  const float* __restrict__ L1,
                                                  const float* __restrict__ bl1,
                                                  const float* __restrict__ L2,
                                                  const float* __restrict__ bl2,
                                                  const float* __restrict__ L3,
                                                  const float* __restrict__ bl3,
                                                  float* __restrict__ out) {
    __shared__ float z[256], z1[128], z2[64];
    const int g = blockIdx.x, tid = threadIdx.x;
    for (int t = tid; t < 256; t += 128)
        z[t] = r1[g * 256 + t] + r2[g * 256 + t] + r3[g * 256 + t];
    __syncthreads();
    {
        float a = bl1[tid];
        for (int i = 0; i < 256; ++i) a += z[i] * L1[i * 128 + tid];
        z1[tid] = fmaxf(a, 0.f);
    }
    __syncthreads();
    if (tid < 64) {
        float a = bl2[tid];
        for (int i = 0; i < 128; ++i) a += z1[i] * L2[i * 64 + tid];
        z2[tid] = fmaxf(a, 0.f);
    }
    __syncthreads();
    if (tid == 0) {
        float l0 = bl3[0], l1v = bl3[1];
        for (int i = 0; i < 64; ++i) {
            l0  += z2[i] * L3[i * 2 + 0];
            l1v += z2[i] * L3[i * 2 + 1];
        }
        float m = fmaxf(l0, l1v);
        float lse = m + logf(expf(l0 - m) + expf(l1v - m));
        out[g * 2 + 0] = l0 - lse;
        out[g * 2 + 1] = l1v - lse;
    }
}

extern "C" void kernel_launch(void* const* d_in, const int* in_sizes, int n_in,
                              void* d_out, int out_size, void* d_ws, size_t ws_size,
                              hipStream_t stream) {
    const float* x   = (const float*)d_in[0];
    const int*  src0 = (const int*)d_in[1];
    const int*  dst0 = (const int*)d_in[2];
    const float* W1 = (const float*)d_in[3];  const float* b1  = (const float*)d_in[4];
    const float* W2 = (const float*)d_in[5];  const float* b2  = (const float*)d_in[6];
    const float* W3 = (const float*)d_in[7];  const float* b3  = (const float*)d_in[8];
    const float* p1 = (const float*)d_in[9];  const float* p2  = (const float*)d_in[10];
    const float* p3 = (const float*)d_in[11];
    const float* L1 = (const float*)d_in[12]; const float* bl1 = (const float*)d_in[13];
    const float* L2 = (const float*)d_in[14]; const float* bl2 = (const float*)d_in[15];
    const float* L3 = (const float*)d_in[16]; const float* bl3 = (const float*)d_in[17];
    float* out = (float*)d_out;

    char* wptr = (char*)d_ws;
    auto alloc = [&](size_t bytes) {
        char* r = wptr;
        wptr += (bytes + 255) & ~(size_t)255;
        return r;
    };
    float* hpre = (float*)alloc(65536ULL * FD * 4);
    float* hbuf = (float*)alloc(65536ULL * FD * 4);
    float* xp2  = (float*)alloc(32768ULL * FD * 4);
    float* xp3  = (float*)alloc(16384ULL * FD * 4);
    float* xp4  = (float*)alloc(8192ULL * FD * 4);
    float* dinv = (float*)alloc(65536ULL * 4);
    int*   nid  = (int*)alloc(65536ULL * 4);
    int*   src1 = (int*)alloc(NE * 4);
    int*   dst1 = (int*)alloc(NE * 4);
    float* ew1  = (float*)alloc(NE * 4);
    int*   src2 = (int*)alloc(NE * 4);
    int*   dst2 = (int*)alloc(NE * 4);
    float* ew2  = (float*)alloc(NE * 4);
    int*   roff = (int*)alloc((size_t)NB * 513 * 4);
    int*   csrc = (int*)alloc((size_t)NE * 4);
    float* ccoef= (float*)alloc((size_t)NE * 4);
    float* r1   = (float*)alloc(128ULL * 256 * 4);
    float* r2   = (float*)alloc(128ULL * 256 * 4);
    float* r3   = (float*)alloc(128ULL * 256 * 4);

    // ---- stage 1 (n_per=512 -> k=256) ----
    gemm128<<<2048, 256, 0, stream>>>(x, W1, hpre);
    build_csr<<<NB, 256, 0, stream>>>(src0, dst0, nullptr, 512, dinv, roff, csrc, ccoef);
    agg_csr<<<65536 / 2, 256, 0, stream>>>(hpre, roff, csrc, ccoef, dinv, b1, 9, hbuf);
    pool_kernel<<<NB, 256, 0, stream>>>(hbuf, p1, 512, 256, xp2, nid);
    relabel_kernel<<<NE / 256, 256, 0, stream>>>(src0, dst0, nullptr, nid, src1, dst1, ew1);
    readout_kernel<<<NB, 128, 0, stream>>>(xp2, 256, r1);

    // ---- stage 2 (n_per=256 -> k=128) ----
    gemm128<<<1024, 256, 0, stream>>>(xp2, W2, hpre);
    build_csr<<<NB, 256, 0, stream>>>(src1, dst1, ew1, 256, dinv, roff, csrc, ccoef);
    agg_csr<<<32768 / 2, 256, 0, stream>>>(hpre, roff, csrc, ccoef, dinv, b2, 8, hbuf);
    pool_kernel<<<NB, 256, 0, stream>>>(hbuf, p2, 256, 128, xp3, nid);
    relabel_kernel<<<NE / 256, 256, 0, stream>>>(src1, dst1, ew1, nid, src2, dst2, ew2);
    readout_kernel<<<NB, 128, 0, stream>>>(xp3, 128, r2);

    // ---- stage 3 (n_per=128 -> k=64) ----
    gemm128<<<512, 256, 0, stream>>>(xp3, W3, hpre);
    build_csr<<<NB, 256, 0, stream>>>(src2, dst2, ew2, 128, dinv, roff, csrc, ccoef);
    agg_csr<<<16384 / 2, 256, 0, stream>>>(hpre, roff, csrc, ccoef, dinv, b3, 7, hbuf);
    pool_kernel<<<NB, 256, 0, stream>>>(hbuf, p3, 128, 64, xp4, nid);
    readout_kernel<<<NB, 128, 0, stream>>>(xp4, 64, r3);

    // ---- final MLP ----
    mlp_kernel<<<NB, 128, 0, stream>>>(r1, r2, r3, L1, bl1, L2, bl2, L3, bl3, out);
}

// Round 5
// 515.056 us; speedup vs baseline: 1.6025x; 1.0858x over previous
//
#include <hip/hip_runtime.h>
#include <math.h>

#define NB 128          // batch of graphs
#define E_PER 2048
#define NE (NB * E_PER) // 262144 edges
#define FD 128          // feature dim (F_IN = NHID)

// ---------------- GEMM: C[N x 128] = A[N x 128] @ W[128 x 128] (f32) ----------
// 128x128 tile / block, 256 threads, K chunked by 32. LDS ~33 KB -> 4 blocks/CU.
// At stride 132: bank=(k+row)%32 -> conflict-free transposed stores, aligned reads.
__global__ __launch_bounds__(256) void gemm128_v2(const float* __restrict__ A,
                                                  const float* __restrict__ W,
                                                  float* __restrict__ C) {
    __shared__ float At[32 * 132];   // [k][row], padded stride 132 (16.9 KB)
    __shared__ float Wt[32 * 128];   // [k][col] (16 KB)
    const int tid = threadIdx.x;
    const long rbase = (long)blockIdx.x * 128;
    const int cg = tid & 15;         // col group 0..15
    const int rg = tid >> 4;         // row group 0..15

    float acc[2][2][4][4];
#pragma unroll
    for (int a = 0; a < 2; ++a)
#pragma unroll
        for (int b = 0; b < 2; ++b)
#pragma unroll
            for (int i = 0; i < 4; ++i)
#pragma unroll
                for (int j = 0; j < 4; ++j) acc[a][b][i][j] = 0.f;

    for (int k0 = 0; k0 < 128; k0 += 32) {
        __syncthreads();
#pragma unroll
        for (int q = 0; q < 4; ++q) {
            int idx = tid + 256 * q;          // 0..1023
            int row = idx >> 3, kq = idx & 7; // coalesced: 8 rows x 128B per instr
            float4 a = *(const float4*)&A[(rbase + row) * FD + k0 + kq * 4];
            At[(kq * 4 + 0) * 132 + row] = a.x;
            At[(kq * 4 + 1) * 132 + row] = a.y;
            At[(kq * 4 + 2) * 132 + row] = a.z;
            At[(kq * 4 + 3) * 132 + row] = a.w;
        }
#pragma unroll
        for (int q = 0; q < 4; ++q) {
            int idx = tid + 256 * q;
            int kk = idx >> 5, cq = idx & 31;
            *(float4*)&Wt[kk * 128 + cq * 4] =
                *(const float4*)&W[(k0 + kk) * FD + cq * 4];
        }
        __syncthreads();
#pragma unroll 8
        for (int kk = 0; kk < 32; ++kk) {
            float4 a0 = *(const float4*)&At[kk * 132 + rg * 4];
            float4 a1 = *(const float4*)&At[kk * 132 + 64 + rg * 4];
            float4 b0 = *(const float4*)&Wt[kk * 128 + cg * 4];
            float4 b1 = *(const float4*)&Wt[kk * 128 + 64 + cg * 4];
            float av[2][4] = {{a0.x, a0.y, a0.z, a0.w}, {a1.x, a1.y, a1.z, a1.w}};
            float bv[2][4] = {{b0.x, b0.y, b0.z, b0.w}, {b1.x, b1.y, b1.z, b1.w}};
#pragma unroll
            for (int a = 0; a < 2; ++a)
#pragma unroll
                for (int b = 0; b < 2; ++b)
#pragma unroll
                    for (int i = 0; i < 4; ++i)
#pragma unroll
                        for (int j = 0; j < 4; ++j)
                            acc[a][b][i][j] += av[a][i] * bv[b][j];
        }
    }
#pragma unroll
    for (int a = 0; a < 2; ++a)
#pragma unroll
        for (int i = 0; i < 4; ++i) {
            long row = rbase + a * 64 + rg * 4 + i;
#pragma unroll
            for (int b = 0; b < 2; ++b) {
                float4 o = {acc[a][b][i][0], acc[a][b][i][1],
                            acc[a][b][i][2], acc[a][b][i][3]};
                *(float4*)&C[row * FD + b * 64 + cg * 4] = o;
            }
        }
}

// -------- build per-graph CSR by dst + dinv + edge coefficients ---------------
// one block per graph
__global__ __launch_bounds__(256) void build_csr(const int* __restrict__ src,
                                                 const int* __restrict__ dst,
                                                 const float* __restrict__ ew,
                                                 int n_per,
                                                 float* __restrict__ dinv,
                                                 int* __restrict__ roff,
                                                 int* __restrict__ csrc,
                                                 float* __restrict__ ccoef) {
    __shared__ int   cnt[512];
    __shared__ int   offs[513];
    __shared__ float dl[512];
    const int g = blockIdx.x, tid = threadIdx.x;
    const int ebase = g * E_PER;
    const int nbase = g * n_per;

    for (int i = tid; i < n_per; i += 256) cnt[i] = 0;
    __syncthreads();
    for (int i = tid; i < E_PER; i += 256) {
        float w = ew ? ew[ebase + i] : 1.0f;
        if (w != 0.f) atomicAdd(&cnt[dst[ebase + i] - nbase], 1);
    }
    __syncthreads();
    for (int i = tid; i < n_per; i += 256) {
        float di = rsqrtf(1.0f + (float)cnt[i]);
        dl[i] = di;
        dinv[nbase + i] = di;
    }
    // exclusive scan: serial on thread 0 (correct; cost is negligible at 128 blocks)
    __syncthreads();
    if (tid == 0) {
        int run = 0;
        for (int i = 0; i < n_per; ++i) { offs[i] = run; run += cnt[i]; }
        offs[n_per] = run;
    }
    __syncthreads();
    for (int i = tid; i <= n_per; i += 256)
        roff[g * (n_per + 1) + i] = ebase + offs[i];
    for (int i = tid; i < n_per; i += 256) cnt[i] = offs[i];  // cursors
    __syncthreads();
    for (int i = tid; i < E_PER; i += 256) {
        float w = ew ? ew[ebase + i] : 1.0f;
        if (w != 0.f) {
            int s = src[ebase + i], d = dst[ebase + i];
            int dlo = d - nbase;
            int pos = atomicAdd(&cnt[dlo], 1);
            csrc[ebase + pos]  = s;
            ccoef[ebase + pos] = dl[s - nbase] * dl[dlo] * w;
        }
    }
}

// -------- aggregate via CSR gather: hout = relu(sum + self + bias) ------------
// 2 nodes per block, 128 feature lanes per node
__global__ __launch_bounds__(256) void agg_csr(const float* __restrict__ hpre,
                                               const int* __restrict__ roff,
                                               const int* __restrict__ csrc,
                                               const float* __restrict__ ccoef,
                                               const float* __restrict__ dinv,
                                               const float* __restrict__ bias,
                                               int np_shift,
                                               float* __restrict__ hout) {
    const int tid = threadIdx.x;
    const int node = blockIdx.x * 2 + (tid >> 7);
    const int f = tid & 127;
    const int n_per = 1 << np_shift;
    const int g = node >> np_shift;
    const int nl = node & (n_per - 1);
    const int rbase = g * (n_per + 1) + nl;
    const int e0 = roff[rbase], e1 = roff[rbase + 1];
    float acc = 0.f;
    for (int e = e0; e < e1; ++e)
        acc += hpre[(long)csrc[e] * FD + f] * ccoef[e];
    const float di = dinv[node];
    float v = acc + hpre[(long)node * FD + f] * di * di + bias[f];
    hout[(long)node * FD + f] = fmaxf(v, 0.f);
}

// ---------------- TopK pool: score, sort, gather*tanh, newid -------------------
__global__ __launch_bounds__(256) void pool_kernel(const float* __restrict__ h,
                                                   const float* __restrict__ p,
                                                   int n_per, int k,
                                                   float* __restrict__ xp,
                                                   int* __restrict__ newid) {
    __shared__ float sc[512];
    __shared__ int   sid[512];
    __shared__ float tf[256];
    __shared__ float pl[128];
    __shared__ float red[256];
    const int tid = threadIdx.x;
    const int g = blockIdx.x;
    const int nbase = g * n_per;

    float v = 0.f;
    if (tid < 128) { float pv = p[tid]; pl[tid] = pv; v = pv * pv; }
    red[tid] = v;
    __syncthreads();
    for (int s = 128; s > 0; s >>= 1) {
        if (tid < s) red[tid] += red[tid + s];
        __syncthreads();
    }
    const float invn = 1.0f / sqrtf(red[0]);

    for (int i = tid; i < n_per; i += 256) {
        const float4* hp = (const float4*)&h[(long)(nbase + i) * FD];
        const float4* pp = (const float4*)pl;
        float a = 0.f;
#pragma unroll
        for (int q = 0; q < 32; ++q) {
            float4 hv = hp[q], pv = pp[q];
            a += hv.x * pv.x + hv.y * pv.y + hv.z * pv.z + hv.w * pv.w;
        }
        sc[i] = a * invn;
        sid[i] = i;
    }
    // bitonic sort: descending score, ties -> lower index first
    for (int ksz = 2; ksz <= n_per; ksz <<= 1)
        for (int j = ksz >> 1; j > 0; j >>= 1) {
            __syncthreads();
            for (int i = tid; i < n_per; i += 256) {
                int l = i ^ j;
                if (l > i) {
                    float si = sc[i], slv = sc[l];
                    int ii = sid[i], il = sid[l];
                    bool up = ((i & ksz) == 0);
                    bool before = (si > slv) || (si == slv && ii < il);
                    if (up != before) { sc[i] = slv; sc[l] = si; sid[i] = il; sid[l] = ii; }
                }
            }
        }
    __syncthreads();
    for (int i = tid; i < n_per; i += 256) newid[nbase + i] = -1;
    __syncthreads();
    for (int r = tid; r < k; r += 256) {
        newid[nbase + sid[r]] = g * k + r;
        tf[r] = tanhf(sc[r]);
    }
    __syncthreads();
    for (int t = tid; t < k * FD; t += 256) {
        int r = t >> 7, f = t & 127;
        xp[((long)g * k + r) * FD + f] = h[(long)(nbase + sid[r]) * FD + f] * tf[r];
    }
}

// ---------------- edge relabel + mask ------------------------------------------
__global__ __launch_bounds__(256) void relabel_kernel(const int* __restrict__ src,
                                                      const int* __restrict__ dst,
                                                      const float* __restrict__ ew,
                                                      const int* __restrict__ newid,
                                                      int* __restrict__ nsrc,
                                                      int* __restrict__ ndst,
                                                      float* __restrict__ new_ew) {
    const int e = blockIdx.x * 256 + threadIdx.x;
    int s = src[e], d = dst[e];
    float w = ew ? ew[e] : 1.0f;
    int ns = newid[s], nd = newid[d];
    bool keep = (ns >= 0) && (nd >= 0);
    nsrc[e] = ns > 0 ? ns : 0;
    ndst[e] = nd > 0 ? nd : 0;
    new_ew[e] = keep ? w : 0.f;
}

// ---------------- readout: [max || mean] per graph -----------------------------
__global__ __launch_bounds__(128) void readout_kernel(const float* __restrict__ xp, int k,
                                                      float* __restrict__ r) {
    const int g = blockIdx.x, f = threadIdx.x;
    const float* base = xp + (long)g * k * FD;
    float mx = -INFINITY, sm = 0.f;
    for (int rr = 0; rr < k; ++rr) {
        float v = base[rr * FD + f];
        mx = fmaxf(mx, v);
        sm += v;
    }
    r[g * 256 + f] = mx;
    r[g * 256 + 128 + f] = sm / (float)k;
}

// ---------------- final MLP + log_softmax --------------------------------------
__global__ __launch_bounds__(128) void mlp_kernel(const float* __restrict__ r1,
                                                  const float* __restrict__ r2,
                                                  const float* __restrict__ r3,
                                                  const float* __restrict__ L1,
                                                  const float* __restrict__ bl1,
                                                  const float* __restrict__ L2,
                                                  const float* __restrict__ bl2,
                                                  const float* __restrict__ L3,
                                                  const float* __restrict__ bl3,
                                                  float* __restrict__ out) {
    __shared__ float z[256], z1[128], z2[64];
    const int g = blockIdx.x, tid = threadIdx.x;
    for (int t = tid; t < 256; t += 128)
        z[t] = r1[g * 256 + t] + r2[g * 256 + t] + r3[g * 256 + t];
    __syncthreads();
    {
        float a = bl1[tid];
        for (int i = 0; i < 256; ++i) a += z[i] * L1[i * 128 + tid];
        z1[tid] = fmaxf(a, 0.f);
    }
    __syncthreads();
    if (tid < 64) {
        float a = bl2[tid];
        for (int i = 0; i < 128; ++i) a += z1[i] * L2[i * 64 + tid];
        z2[tid] = fmaxf(a, 0.f);
    }
    __syncthreads();
    if (tid == 0) {
        float l0 = bl3[0], l1v = bl3[1];
        for (int i = 0; i < 64; ++i) {
            l0  += z2[i] * L3[i * 2 + 0];
            l1v += z2[i] * L3[i * 2 + 1];
        }
        float m = fmaxf(l0, l1v);
        float lse = m + logf(expf(l0 - m) + expf(l1v - m));
        out[g * 2 + 0] = l0 - lse;
        out[g * 2 + 1] = l1v - lse;
    }
}

extern "C" void kernel_launch(void* const* d_in, const int* in_sizes, int n_in,
                              void* d_out, int out_size, void* d_ws, size_t ws_size,
                              hipStream_t stream) {
    const float* x   = (const float*)d_in[0];
    const int*  src0 = (const int*)d_in[1];
    const int*  dst0 = (const int*)d_in[2];
    const float* W1 = (const float*)d_in[3];  const float* b1  = (const float*)d_in[4];
    const float* W2 = (const float*)d_in[5];  const float* b2  = (const float*)d_in[6];
    const float* W3 = (const float*)d_in[7];  const float* b3  = (const float*)d_in[8];
    const float* p1 = (const float*)d_in[9];  const float* p2  = (const float*)d_in[10];
    const float* p3 = (const float*)d_in[11];
    const float* L1 = (const float*)d_in[12]; const float* bl1 = (const float*)d_in[13];
    const float* L2 = (const float*)d_in[14]; const float* bl2 = (const float*)d_in[15];
    const float* L3 = (const float*)d_in[16]; const float* bl3 = (const float*)d_in[17];
    float* out = (float*)d_out;

    char* wptr = (char*)d_ws;
    auto alloc = [&](size_t bytes) {
        char* r = wptr;
        wptr += (bytes + 255) & ~(size_t)255;
        return r;
    };
    float* hpre = (float*)alloc(65536ULL * FD * 4);
    float* hbuf = (float*)alloc(65536ULL * FD * 4);
    float* xp2  = (float*)alloc(32768ULL * FD * 4);
    float* xp3  = (float*)alloc(16384ULL * FD * 4);
    float* xp4  = (float*)alloc(8192ULL * FD * 4);
    float* dinv = (float*)alloc(65536ULL * 4);
    int*   nid  = (int*)alloc(65536ULL * 4);
    int*   src1 = (int*)alloc(NE * 4);
    int*   dst1 = (int*)alloc(NE * 4);
    float* ew1  = (float*)alloc(NE * 4);
    int*   src2 = (int*)alloc(NE * 4);
    int*   dst2 = (int*)alloc(NE * 4);
    float* ew2  = (float*)alloc(NE * 4);
    int*   roff = (int*)alloc((size_t)NB * 513 * 4);
    int*   csrc = (int*)alloc((size_t)NE * 4);
    float* ccoef= (float*)alloc((size_t)NE * 4);
    float* r1   = (float*)alloc(128ULL * 256 * 4);
    float* r2   = (float*)alloc(128ULL * 256 * 4);
    float* r3   = (float*)alloc(128ULL * 256 * 4);

    // ---- stage 1 (n_per=512 -> k=256) ----
    gemm128_v2<<<512, 256, 0, stream>>>(x, W1, hpre);
    build_csr<<<NB, 256, 0, stream>>>(src0, dst0, nullptr, 512, dinv, roff, csrc, ccoef);
    agg_csr<<<65536 / 2, 256, 0, stream>>>(hpre, roff, csrc, ccoef, dinv, b1, 9, hbuf);
    pool_kernel<<<NB, 256, 0, stream>>>(hbuf, p1, 512, 256, xp2, nid);
    relabel_kernel<<<NE / 256, 256, 0, stream>>>(src0, dst0, nullptr, nid, src1, dst1, ew1);
    readout_kernel<<<NB, 128, 0, stream>>>(xp2, 256, r1);

    // ---- stage 2 (n_per=256 -> k=128) ----
    gemm128_v2<<<256, 256, 0, stream>>>(xp2, W2, hpre);
    build_csr<<<NB, 256, 0, stream>>>(src1, dst1, ew1, 256, dinv, roff, csrc, ccoef);
    agg_csr<<<32768 / 2, 256, 0, stream>>>(hpre, roff, csrc, ccoef, dinv, b2, 8, hbuf);
    pool_kernel<<<NB, 256, 0, stream>>>(hbuf, p2, 256, 128, xp3, nid);
    relabel_kernel<<<NE / 256, 256, 0, stream>>>(src1, dst1, ew1, nid, src2, dst2, ew2);
    readout_kernel<<<NB, 128, 0, stream>>>(xp3, 128, r2);

    // ---- stage 3 (n_per=128 -> k=64) ----
    gemm128_v2<<<128, 256, 0, stream>>>(xp3, W3, hpre);
    build_csr<<<NB, 256, 0, stream>>>(src2, dst2, ew2, 128, dinv, roff, csrc, ccoef);
    agg_csr<<<16384 / 2, 256, 0, stream>>>(hpre, roff, csrc, ccoef, dinv, b3, 7, hbuf);
    pool_kernel<<<NB, 256, 0, stream>>>(hbuf, p3, 128, 64, xp4, nid);
    readout_kernel<<<NB, 128, 0, stream>>>(xp4, 64, r3);

    // ---- final MLP ----
    mlp_kernel<<<NB, 128, 0, stream>>>(r1, r2, r3, L1, bl1, L2, bl2, L3, bl3, out);
}

// Round 6
// 447.120 us; speedup vs baseline: 1.8460x; 1.1519x over previous
//
#include <hip/hip_runtime.h>
#include <math.h>

#define NB 128          // batch of graphs
#define E_PER 2048
#define NE (NB * E_PER) // 262144 edges
#define FD 128          // feature dim (F_IN = NHID)

// ---------------- GEMM: C[N x 128] = A[N x 128] @ W[128 x 128] (f32) ----------
// 128x128 tile / block, 256 threads, K chunked by 32. LDS ~33 KB -> 4 blocks/CU.
__global__ __launch_bounds__(256) void gemm128_v2(const float* __restrict__ A,
                                                  const float* __restrict__ W,
                                                  float* __restrict__ C) {
    __shared__ float At[32 * 132];   // [k][row], padded stride 132 (16.9 KB)
    __shared__ float Wt[32 * 128];   // [k][col] (16 KB)
    const int tid = threadIdx.x;
    const long rbase = (long)blockIdx.x * 128;
    const int cg = tid & 15;         // col group 0..15
    const int rg = tid >> 4;         // row group 0..15

    float acc[2][2][4][4];
#pragma unroll
    for (int a = 0; a < 2; ++a)
#pragma unroll
        for (int b = 0; b < 2; ++b)
#pragma unroll
            for (int i = 0; i < 4; ++i)
#pragma unroll
                for (int j = 0; j < 4; ++j) acc[a][b][i][j] = 0.f;

    for (int k0 = 0; k0 < 128; k0 += 32) {
        __syncthreads();
#pragma unroll
        for (int q = 0; q < 4; ++q) {
            int idx = tid + 256 * q;          // 0..1023
            int row = idx >> 3, kq = idx & 7; // coalesced: 8 rows x 128B per instr
            float4 a = *(const float4*)&A[(rbase + row) * FD + k0 + kq * 4];
            At[(kq * 4 + 0) * 132 + row] = a.x;
            At[(kq * 4 + 1) * 132 + row] = a.y;
            At[(kq * 4 + 2) * 132 + row] = a.z;
            At[(kq * 4 + 3) * 132 + row] = a.w;
        }
#pragma unroll
        for (int q = 0; q < 4; ++q) {
            int idx = tid + 256 * q;
            int kk = idx >> 5, cq = idx & 31;
            *(float4*)&Wt[kk * 128 + cq * 4] =
                *(const float4*)&W[(k0 + kk) * FD + cq * 4];
        }
        __syncthreads();
#pragma unroll 8
        for (int kk = 0; kk < 32; ++kk) {
            float4 a0 = *(const float4*)&At[kk * 132 + rg * 4];
            float4 a1 = *(const float4*)&At[kk * 132 + 64 + rg * 4];
            float4 b0 = *(const float4*)&Wt[kk * 128 + cg * 4];
            float4 b1 = *(const float4*)&Wt[kk * 128 + 64 + cg * 4];
            float av[2][4] = {{a0.x, a0.y, a0.z, a0.w}, {a1.x, a1.y, a1.z, a1.w}};
            float bv[2][4] = {{b0.x, b0.y, b0.z, b0.w}, {b1.x, b1.y, b1.z, b1.w}};
#pragma unroll
            for (int a = 0; a < 2; ++a)
#pragma unroll
                for (int b = 0; b < 2; ++b)
#pragma unroll
                    for (int i = 0; i < 4; ++i)
#pragma unroll
                        for (int j = 0; j < 4; ++j)
                            acc[a][b][i][j] += av[a][i] * bv[b][j];
        }
    }
#pragma unroll
    for (int a = 0; a < 2; ++a)
#pragma unroll
        for (int i = 0; i < 4; ++i) {
            long row = rbase + a * 64 + rg * 4 + i;
#pragma unroll
            for (int b = 0; b < 2; ++b) {
                float4 o = {acc[a][b][i][0], acc[a][b][i][1],
                            acc[a][b][i][2], acc[a][b][i][3]};
                *(float4*)&C[row * FD + b * 64 + cg * 4] = o;
            }
        }
}

// -------- build per-graph CSR by dst + dinv + edge coefficients ---------------
__global__ __launch_bounds__(256) void build_csr(const int* __restrict__ src,
                                                 const int* __restrict__ dst,
                                                 const float* __restrict__ ew,
                                                 int n_per,
                                                 float* __restrict__ dinv,
                                                 int* __restrict__ roff,
                                                 int* __restrict__ csrc,
                                                 float* __restrict__ ccoef) {
    __shared__ int   cnt[512];
    __shared__ int   offs[513];
    __shared__ float dl[512];
    const int g = blockIdx.x, tid = threadIdx.x;
    const int ebase = g * E_PER;
    const int nbase = g * n_per;

    for (int i = tid; i < n_per; i += 256) cnt[i] = 0;
    __syncthreads();
    for (int i = tid; i < E_PER; i += 256) {
        float w = ew ? ew[ebase + i] : 1.0f;
        if (w != 0.f) atomicAdd(&cnt[dst[ebase + i] - nbase], 1);
    }
    __syncthreads();
    for (int i = tid; i < n_per; i += 256) {
        float di = rsqrtf(1.0f + (float)cnt[i]);
        dl[i] = di;
        dinv[nbase + i] = di;
    }
    // exclusive scan: serial on thread 0 (correct; cost negligible at 128 blocks)
    __syncthreads();
    if (tid == 0) {
        int run = 0;
        for (int i = 0; i < n_per; ++i) { offs[i] = run; run += cnt[i]; }
        offs[n_per] = run;
    }
    __syncthreads();
    for (int i = tid; i <= n_per; i += 256)
        roff[g * (n_per + 1) + i] = ebase + offs[i];
    for (int i = tid; i < n_per; i += 256) cnt[i] = offs[i];  // cursors
    __syncthreads();
    for (int i = tid; i < E_PER; i += 256) {
        float w = ew ? ew[ebase + i] : 1.0f;
        if (w != 0.f) {
            int s = src[ebase + i], d = dst[ebase + i];
            int dlo = d - nbase;
            int pos = atomicAdd(&cnt[dlo], 1);
            csrc[ebase + pos]  = s;
            ccoef[ebase + pos] = dl[s - nbase] * dl[dlo] * w;
        }
    }
}

// -------- aggregate via CSR gather: hout = relu(sum + self + bias) ------------
__global__ __launch_bounds__(256) void agg_csr(const float* __restrict__ hpre,
                                               const int* __restrict__ roff,
                                               const int* __restrict__ csrc,
                                               const float* __restrict__ ccoef,
                                               const float* __restrict__ dinv,
                                               const float* __restrict__ bias,
                                               int np_shift,
                                               float* __restrict__ hout) {
    const int tid = threadIdx.x;
    const int node = blockIdx.x * 2 + (tid >> 7);
    const int f = tid & 127;
    const int n_per = 1 << np_shift;
    const int g = node >> np_shift;
    const int nl = node & (n_per - 1);
    const int rbase = g * (n_per + 1) + nl;
    const int e0 = roff[rbase], e1 = roff[rbase + 1];
    float acc = 0.f;
    for (int e = e0; e < e1; ++e)
        acc += hpre[(long)csrc[e] * FD + f] * ccoef[e];
    const float di = dinv[node];
    float v = acc + hpre[(long)node * FD + f] * di * di + bias[f];
    hout[(long)node * FD + f] = fmaxf(v, 0.f);
}

// ------- TopK pool: score, sort, gather*tanh, newid + FUSED readout -----------
__global__ __launch_bounds__(256) void pool_kernel(const float* __restrict__ h,
                                                   const float* __restrict__ p,
                                                   int n_per, int k,
                                                   float* __restrict__ xp,
                                                   int* __restrict__ newid,
                                                   float* __restrict__ rout) {
    __shared__ float sc[512];
    __shared__ int   sid[512];
    __shared__ float tf[256];
    __shared__ float pl[128];
    __shared__ float red[256];
    const int tid = threadIdx.x;
    const int g = blockIdx.x;
    const int nbase = g * n_per;

    float v = 0.f;
    if (tid < 128) { float pv = p[tid]; pl[tid] = pv; v = pv * pv; }
    red[tid] = v;
    __syncthreads();
    for (int s = 128; s > 0; s >>= 1) {
        if (tid < s) red[tid] += red[tid + s];
        __syncthreads();
    }
    const float invn = 1.0f / sqrtf(red[0]);

    for (int i = tid; i < n_per; i += 256) {
        const float4* hp = (const float4*)&h[(long)(nbase + i) * FD];
        const float4* pp = (const float4*)pl;
        float a = 0.f;
#pragma unroll
        for (int q = 0; q < 32; ++q) {
            float4 hv = hp[q], pv = pp[q];
            a += hv.x * pv.x + hv.y * pv.y + hv.z * pv.z + hv.w * pv.w;
        }
        sc[i] = a * invn;
        sid[i] = i;
    }
    // bitonic sort: descending score, ties -> lower index first
    for (int ksz = 2; ksz <= n_per; ksz <<= 1)
        for (int j = ksz >> 1; j > 0; j >>= 1) {
            __syncthreads();
            for (int i = tid; i < n_per; i += 256) {
                int l = i ^ j;
                if (l > i) {
                    float si = sc[i], slv = sc[l];
                    int ii = sid[i], il = sid[l];
                    bool up = ((i & ksz) == 0);
                    bool before = (si > slv) || (si == slv && ii < il);
                    if (up != before) { sc[i] = slv; sc[l] = si; sid[i] = il; sid[l] = ii; }
                }
            }
        }
    __syncthreads();
    for (int i = tid; i < n_per; i += 256) newid[nbase + i] = -1;
    __syncthreads();
    for (int r = tid; r < k; r += 256) {
        newid[nbase + sid[r]] = g * k + r;
        tf[r] = tanhf(sc[r]);
    }
    __syncthreads();
    // gather + fused [max || mean] readout. f = tid&127 is FIXED per thread;
    // two thread groups (tid<128 / >=128) cover interleaved r.
    const int f = tid & 127;
    float mx = -INFINITY, sm = 0.f;
    for (int t = tid; t < k * FD; t += 256) {
        int r = t >> 7;
        float val = h[(long)(nbase + sid[r]) * FD + f] * tf[r];
        xp[((long)g * k + r) * FD + f] = val;
        mx = fmaxf(mx, val);
        sm += val;
    }
    __syncthreads();                 // sc no longer needed -> reuse as reduction buf
    float* mxs = sc;
    float* sms = sc + 128;
    if (tid < 128) { mxs[f] = mx; sms[f] = sm; }
    __syncthreads();
    if (tid >= 128) { mxs[f] = fmaxf(mxs[f], mx); sms[f] += sm; }
    __syncthreads();
    if (tid < 128) {
        rout[g * 256 + f] = mxs[f];
        rout[g * 256 + 128 + f] = sms[f] / (float)k;
    }
}

// ---------------- edge relabel + mask ------------------------------------------
__global__ __launch_bounds__(256) void relabel_kernel(const int* __restrict__ src,
                                                      const int* __restrict__ dst,
                                                      const float* __restrict__ ew,
                                                      const int* __restrict__ newid,
                                                      int* __restrict__ nsrc,
                                                      int* __restrict__ ndst,
                                                      float* __restrict__ new_ew) {
    const int e = blockIdx.x * 256 + threadIdx.x;
    int s = src[e], d = dst[e];
    float w = ew ? ew[e] : 1.0f;
    int ns = newid[s], nd = newid[d];
    bool keep = (ns >= 0) && (nd >= 0);
    nsrc[e] = ns > 0 ? ns : 0;
    ndst[e] = nd > 0 ? nd : 0;
    new_ew[e] = keep ? w : 0.f;
}

// ---------------- final MLP + log_softmax --------------------------------------
__global__ __launch_bounds__(128) void mlp_kernel(const float* __restrict__ r1,
                                                  const float* __restrict__ r2,
                                                  const float* __restrict__ r3,
                                                  const float* __restrict__ L1,
                                                  const float* __restrict__ bl1,
                                                  const float* __restrict__ L2,
                                                  const float* __restrict__ bl2,
                                                  const float* __restrict__ L3,
                                                  const float* __restrict__ bl3,
                                                  float* __restrict__ out) {
    __shared__ float z[256], z1[128], z2[64];
    const int g = blockIdx.x, tid = threadIdx.x;
    for (int t = tid; t < 256; t += 128)
        z[t] = r1[g * 256 + t] + r2[g * 256 + t] + r3[g * 256 + t];
    __syncthreads();
    {
        float a = bl1[tid];
        for (int i = 0; i < 256; ++i) a += z[i] * L1[i * 128 + tid];
        z1[tid] = fmaxf(a, 0.f);
    }
    __syncthreads();
    if (tid < 64) {
        float a = bl2[tid];
        for (int i = 0; i < 128; ++i) a += z1[i] * L2[i * 64 + tid];
        z2[tid] = fmaxf(a, 0.f);
    }
    __syncthreads();
    if (tid == 0) {
        float l0 = bl3[0], l1v = bl3[1];
        for (int i = 0; i < 64; ++i) {
            l0  += z2[i] * L3[i * 2 + 0];
            l1v += z2[i] * L3[i * 2 + 1];
        }
        float m = fmaxf(l0, l1v);
        float lse = m + logf(expf(l0 - m) + expf(l1v - m));
        out[g * 2 + 0] = l0 - lse;
        out[g * 2 + 1] = l1v - lse;
    }
}

extern "C" void kernel_launch(void* const* d_in, const int* in_sizes, int n_in,
                              void* d_out, int out_size, void* d_ws, size_t ws_size,
                              hipStream_t stream) {
    const float* x   = (const float*)d_in[0];
    const int*  src0 = (const int*)d_in[1];
    const int*  dst0 = (const int*)d_in[2];
    const float* W1 = (const float*)d_in[3];  const float* b1  = (const float*)d_in[4];
    const float* W2 = (const float*)d_in[5];  const float* b2  = (const float*)d_in[6];
    const float* W3 = (const float*)d_in[7];  const float* b3  = (const float*)d_in[8];
    const float* p1 = (const float*)d_in[9];  const float* p2  = (const float*)d_in[10];
    const float* p3 = (const float*)d_in[11];
    const float* L1 = (const float*)d_in[12]; const float* bl1 = (const float*)d_in[13];
    const float* L2 = (const float*)d_in[14]; const float* bl2 = (const float*)d_in[15];
    const float* L3 = (const float*)d_in[16]; const float* bl3 = (const float*)d_in[17];
    float* out = (float*)d_out;

    char* wptr = (char*)d_ws;
    auto alloc = [&](size_t bytes) {
        char* r = wptr;
        wptr += (bytes + 255) & ~(size_t)255;
        return r;
    };
    float* hpre = (float*)alloc(65536ULL * FD * 4);
    float* hbuf = (float*)alloc(65536ULL * FD * 4);
    float* xp2  = (float*)alloc(32768ULL * FD * 4);
    float* xp3  = (float*)alloc(16384ULL * FD * 4);
    float* xp4  = (float*)alloc(8192ULL * FD * 4);
    float* dinv = (float*)alloc(65536ULL * 4);
    int*   nid  = (int*)alloc(65536ULL * 4);
    int*   src1 = (int*)alloc(NE * 4);
    int*   dst1 = (int*)alloc(NE * 4);
    float* ew1  = (float*)alloc(NE * 4);
    int*   src2 = (int*)alloc(NE * 4);
    int*   dst2 = (int*)alloc(NE * 4);
    float* ew2  = (float*)alloc(NE * 4);
    int*   roff = (int*)alloc((size_t)NB * 513 * 4);
    int*   csrc = (int*)alloc((size_t)NE * 4);
    float* ccoef= (float*)alloc((size_t)NE * 4);
    float* r1   = (float*)alloc(128ULL * 256 * 4);
    float* r2   = (float*)alloc(128ULL * 256 * 4);
    float* r3   = (float*)alloc(128ULL * 256 * 4);

    // ---- stage 1 (n_per=512 -> k=256) ----
    gemm128_v2<<<512, 256, 0, stream>>>(x, W1, hpre);
    build_csr<<<NB, 256, 0, stream>>>(src0, dst0, nullptr, 512, dinv, roff, csrc, ccoef);
    agg_csr<<<65536 / 2, 256, 0, stream>>>(hpre, roff, csrc, ccoef, dinv, b1, 9, hbuf);
    pool_kernel<<<NB, 256, 0, stream>>>(hbuf, p1, 512, 256, xp2, nid, r1);
    relabel_kernel<<<NE / 256, 256, 0, stream>>>(src0, dst0, nullptr, nid, src1, dst1, ew1);

    // ---- stage 2 (n_per=256 -> k=128) ----
    gemm128_v2<<<256, 256, 0, stream>>>(xp2, W2, hpre);
    build_csr<<<NB, 256, 0, stream>>>(src1, dst1, ew1, 256, dinv, roff, csrc, ccoef);
    agg_csr<<<32768 / 2, 256, 0, stream>>>(hpre, roff, csrc, ccoef, dinv, b2, 8, hbuf);
    pool_kernel<<<NB, 256, 0, stream>>>(hbuf, p2, 256, 128, xp3, nid, r2);
    relabel_kernel<<<NE / 256, 256, 0, stream>>>(src1, dst1, ew1, nid, src2, dst2, ew2);

    // ---- stage 3 (n_per=128 -> k=64) ----
    gemm128_v2<<<128, 256, 0, stream>>>(xp3, W3, hpre);
    build_csr<<<NB, 256, 0, stream>>>(src2, dst2, ew2, 128, dinv, roff, csrc, ccoef);
    agg_csr<<<16384 / 2, 256, 0, stream>>>(hpre, roff, csrc, ccoef, dinv, b3, 7, hbuf);
    pool_kernel<<<NB, 256, 0, stream>>>(hbuf, p3, 128, 64, xp4, nid, r3);

    // ---- final MLP ----
    mlp_kernel<<<NB, 128, 0, stream>>>(r1, r2, r3, L1, bl1, L2, bl2, L3, bl3, out);
}

// Round 7
// 419.640 us; speedup vs baseline: 1.9669x; 1.0655x over previous
//
#include <hip/hip_runtime.h>
#include <math.h>

#define NB 128          // batch of graphs
#define E_PER 2048
#define NE (NB * E_PER) // 262144 edges
#define FD 128          // feature dim (F_IN = NHID)

// ---------------- GEMM: C[N x 128] = A[N x 128] @ W[128 x 128] (f32) ----------
// 128x128 tile / block, 256 threads, K chunked by 32. LDS ~33 KB -> 4 blocks/CU.
__global__ __launch_bounds__(256) void gemm128_v2(const float* __restrict__ A,
                                                  const float* __restrict__ W,
                                                  float* __restrict__ C) {
    __shared__ float At[32 * 132];   // [k][row], padded stride 132 (16.9 KB)
    __shared__ float Wt[32 * 128];   // [k][col] (16 KB)
    const int tid = threadIdx.x;
    const long rbase = (long)blockIdx.x * 128;
    const int cg = tid & 15;         // col group 0..15
    const int rg = tid >> 4;         // row group 0..15

    float acc[2][2][4][4];
#pragma unroll
    for (int a = 0; a < 2; ++a)
#pragma unroll
        for (int b = 0; b < 2; ++b)
#pragma unroll
            for (int i = 0; i < 4; ++i)
#pragma unroll
                for (int j = 0; j < 4; ++j) acc[a][b][i][j] = 0.f;

    for (int k0 = 0; k0 < 128; k0 += 32) {
        __syncthreads();
#pragma unroll
        for (int q = 0; q < 4; ++q) {
            int idx = tid + 256 * q;          // 0..1023
            int row = idx >> 3, kq = idx & 7; // coalesced: 8 rows x 128B per instr
            float4 a = *(const float4*)&A[(rbase + row) * FD + k0 + kq * 4];
            At[(kq * 4 + 0) * 132 + row] = a.x;
            At[(kq * 4 + 1) * 132 + row] = a.y;
            At[(kq * 4 + 2) * 132 + row] = a.z;
            At[(kq * 4 + 3) * 132 + row] = a.w;
        }
#pragma unroll
        for (int q = 0; q < 4; ++q) {
            int idx = tid + 256 * q;
            int kk = idx >> 5, cq = idx & 31;
            *(float4*)&Wt[kk * 128 + cq * 4] =
                *(const float4*)&W[(k0 + kk) * FD + cq * 4];
        }
        __syncthreads();
#pragma unroll 8
        for (int kk = 0; kk < 32; ++kk) {
            float4 a0 = *(const float4*)&At[kk * 132 + rg * 4];
            float4 a1 = *(const float4*)&At[kk * 132 + 64 + rg * 4];
            float4 b0 = *(const float4*)&Wt[kk * 128 + cg * 4];
            float4 b1 = *(const float4*)&Wt[kk * 128 + 64 + cg * 4];
            float av[2][4] = {{a0.x, a0.y, a0.z, a0.w}, {a1.x, a1.y, a1.z, a1.w}};
            float bv[2][4] = {{b0.x, b0.y, b0.z, b0.w}, {b1.x, b1.y, b1.z, b1.w}};
#pragma unroll
            for (int a = 0; a < 2; ++a)
#pragma unroll
                for (int b = 0; b < 2; ++b)
#pragma unroll
                    for (int i = 0; i < 4; ++i)
#pragma unroll
                        for (int j = 0; j < 4; ++j)
                            acc[a][b][i][j] += av[a][i] * bv[b][j];
        }
    }
#pragma unroll
    for (int a = 0; a < 2; ++a)
#pragma unroll
        for (int i = 0; i < 4; ++i) {
            long row = rbase + a * 64 + rg * 4 + i;
#pragma unroll
            for (int b = 0; b < 2; ++b) {
                float4 o = {acc[a][b][i][0], acc[a][b][i][1],
                            acc[a][b][i][2], acc[a][b][i][3]};
                *(float4*)&C[row * FD + b * 64 + cg * 4] = o;
            }
        }
}

// -------- build per-graph CSR by dst + dinv + edge coefficients ---------------
__global__ __launch_bounds__(256) void build_csr(const int* __restrict__ src,
                                                 const int* __restrict__ dst,
                                                 const float* __restrict__ ew,
                                                 int n_per,
                                                 float* __restrict__ dinv,
                                                 int* __restrict__ roff,
                                                 int* __restrict__ csrc,
                                                 float* __restrict__ ccoef) {
    __shared__ int   cnt[512];
    __shared__ int   offs[513];
    __shared__ float dl[512];
    const int g = blockIdx.x, tid = threadIdx.x;
    const int ebase = g * E_PER;
    const int nbase = g * n_per;

    for (int i = tid; i < n_per; i += 256) cnt[i] = 0;
    __syncthreads();
    for (int i = tid; i < E_PER; i += 256) {
        float w = ew ? ew[ebase + i] : 1.0f;
        if (w != 0.f) atomicAdd(&cnt[dst[ebase + i] - nbase], 1);
    }
    __syncthreads();
    for (int i = tid; i < n_per; i += 256) {
        float di = rsqrtf(1.0f + (float)cnt[i]);
        dl[i] = di;
        dinv[nbase + i] = di;
    }
    // exclusive scan: serial on thread 0 (correct; cost negligible at 128 blocks)
    __syncthreads();
    if (tid == 0) {
        int run = 0;
        for (int i = 0; i < n_per; ++i) { offs[i] = run; run += cnt[i]; }
        offs[n_per] = run;
    }
    __syncthreads();
    for (int i = tid; i <= n_per; i += 256)
        roff[g * (n_per + 1) + i] = ebase + offs[i];
    for (int i = tid; i < n_per; i += 256) cnt[i] = offs[i];  // cursors
    __syncthreads();
    for (int i = tid; i < E_PER; i += 256) {
        float w = ew ? ew[ebase + i] : 1.0f;
        if (w != 0.f) {
            int s = src[ebase + i], d = dst[ebase + i];
            int dlo = d - nbase;
            int pos = atomicAdd(&cnt[dlo], 1);
            csrc[ebase + pos]  = s;
            ccoef[ebase + pos] = dl[s - nbase] * dl[dlo] * w;
        }
    }
}

// -------- aggregate via CSR gather: hout = relu(sum + self + bias) ------------
__global__ __launch_bounds__(256) void agg_csr(const float* __restrict__ hpre,
                                               const int* __restrict__ roff,
                                               const int* __restrict__ csrc,
                                               const float* __restrict__ ccoef,
                                               const float* __restrict__ dinv,
                                               const float* __restrict__ bias,
                                               int np_shift,
                                               float* __restrict__ hout) {
    const int tid = threadIdx.x;
    const int node = blockIdx.x * 2 + (tid >> 7);
    const int f = tid & 127;
    const int n_per = 1 << np_shift;
    const int g = node >> np_shift;
    const int nl = node & (n_per - 1);
    const int rbase = g * (n_per + 1) + nl;
    const int e0 = roff[rbase], e1 = roff[rbase + 1];
    float acc = 0.f;
    for (int e = e0; e < e1; ++e)
        acc += hpre[(long)csrc[e] * FD + f] * ccoef[e];
    const float di = dinv[node];
    float v = acc + hpre[(long)node * FD + f] * di * di + bias[f];
    hout[(long)node * FD + f] = fmaxf(v, 0.f);
}

// ------- TopK pool: score, RANK-select (no sort), gather*tanh + readout -------
// rank[i] = #{j: s[j]>s[i] or (s[j]==s[i] and j<i)} == stable desc-sort position
// (exact jax.lax.top_k semantics, zero barriers, pure LDS broadcast reads)
__global__ __launch_bounds__(512) void pool_kernel(const float* __restrict__ h,
                                                   const float* __restrict__ p,
                                                   int n_per, int k,
                                                   float* __restrict__ xp,
                                                   int* __restrict__ newid,
                                                   float* __restrict__ rout) {
    __shared__ float sc[512];
    __shared__ int   ord[256];   // rank -> local node idx (k <= 256)
    __shared__ float tf[256];    // tanh(score) by rank
    __shared__ float pl[128];
    __shared__ float red[128];
    __shared__ float mxs[512];
    __shared__ float sms[512];
    const int tid = threadIdx.x;
    const int g = blockIdx.x;
    const int nbase = g * n_per;

    if (tid < 128) { float pv = p[tid]; pl[tid] = pv; red[tid] = pv * pv; }
    __syncthreads();
    for (int s = 64; s > 0; s >>= 1) {
        if (tid < s) red[tid] += red[tid + s];
        __syncthreads();
    }
    const float invn = rsqrtf(red[0]);

    // scores: one row per thread
    if (tid < n_per) {
        const float4* hp = (const float4*)&h[(long)(nbase + tid) * FD];
        const float4* pp = (const float4*)pl;
        float a = 0.f;
#pragma unroll
        for (int q = 0; q < 32; ++q) {
            float4 hv = hp[q], pv = pp[q];
            a += hv.x * pv.x + hv.y * pv.y + hv.z * pv.z + hv.w * pv.w;
        }
        sc[tid] = a * invn;
    }
    __syncthreads();

    // rank + scatter
    if (tid < n_per) {
        const float si = sc[tid];
        int rank = 0;
        for (int j = 0; j < n_per; ++j) {
            float sj = sc[j];
            rank += (sj > si) || (sj == si && j < tid);
        }
        if (rank < k) {
            ord[rank] = tid;
            tf[rank] = tanhf(si);
            newid[nbase + tid] = g * k + rank;
        } else {
            newid[nbase + tid] = -1;
        }
    }
    __syncthreads();

    // gather + fused [max || mean] readout. f = tid&127 fixed per thread.
    const int f = tid & 127;
    const int grp = tid >> 7;    // 0..3
    float mx = -INFINITY, sm = 0.f;
    for (int t = tid; t < k * FD; t += 512) {
        int r = t >> 7;
        float val = h[(long)(nbase + ord[r]) * FD + f] * tf[r];
        xp[((long)g * k + r) * FD + f] = val;
        mx = fmaxf(mx, val);
        sm += val;
    }
    mxs[grp * 128 + f] = mx;
    sms[grp * 128 + f] = sm;
    __syncthreads();
    if (tid < 128) {
        float m0 = fmaxf(fmaxf(mxs[f], mxs[128 + f]), fmaxf(mxs[256 + f], mxs[384 + f]));
        float s0 = sms[f] + sms[128 + f] + sms[256 + f] + sms[384 + f];
        rout[g * 256 + f] = m0;
        rout[g * 256 + 128 + f] = s0 / (float)k;
    }
}

// ---------------- edge relabel + mask ------------------------------------------
__global__ __launch_bounds__(256) void relabel_kernel(const int* __restrict__ src,
                                                      const int* __restrict__ dst,
                                                      const float* __restrict__ ew,
                                                      const int* __restrict__ newid,
                                                      int* __restrict__ nsrc,
                                                      int* __restrict__ ndst,
                                                      float* __restrict__ new_ew) {
    const int e = blockIdx.x * 256 + threadIdx.x;
    int s = src[e], d = dst[e];
    float w = ew ? ew[e] : 1.0f;
    int ns = newid[s], nd = newid[d];
    bool keep = (ns >= 0) && (nd >= 0);
    nsrc[e] = ns > 0 ? ns : 0;
    ndst[e] = nd > 0 ? nd : 0;
    new_ew[e] = keep ? w : 0.f;
}

// ---------------- final MLP + log_softmax --------------------------------------
__global__ __launch_bounds__(128) void mlp_kernel(const float* __restrict__ r1,
                                                  const float* __restrict__ r2,
                                                  const float* __restrict__ r3,
                                                  const float* __restrict__ L1,
                                                  const float* __restrict__ bl1,
                                                  const float* __restrict__ L2,
                                                  const float* __restrict__ bl2,
                                                  const float* __restrict__ L3,
                                                  const float* __restrict__ bl3,
                                                  float* __restrict__ out) {
    __shared__ float z[256], z1[128], z2[64];
    const int g = blockIdx.x, tid = threadIdx.x;
    for (int t = tid; t < 256; t += 128)
        z[t] = r1[g * 256 + t] + r2[g * 256 + t] + r3[g * 256 + t];
    __syncthreads();
    {
        float a = bl1[tid];
        for (int i = 0; i < 256; ++i) a += z[i] * L1[i * 128 + tid];
        z1[tid] = fmaxf(a, 0.f);
    }
    __syncthreads();
    if (tid < 64) {
        float a = bl2[tid];
        for (int i = 0; i < 128; ++i) a += z1[i] * L2[i * 64 + tid];
        z2[tid] = fmaxf(a, 0.f);
    }
    __syncthreads();
    if (tid == 0) {
        float l0 = bl3[0], l1v = bl3[1];
        for (int i = 0; i < 64; ++i) {
            l0  += z2[i] * L3[i * 2 + 0];
            l1v += z2[i] * L3[i * 2 + 1];
        }
        float m = fmaxf(l0, l1v);
        float lse = m + logf(expf(l0 - m) + expf(l1v - m));
        out[g * 2 + 0] = l0 - lse;
        out[g * 2 + 1] = l1v - lse;
    }
}

extern "C" void kernel_launch(void* const* d_in, const int* in_sizes, int n_in,
                              void* d_out, int out_size, void* d_ws, size_t ws_size,
                              hipStream_t stream) {
    const float* x   = (const float*)d_in[0];
    const int*  src0 = (const int*)d_in[1];
    const int*  dst0 = (const int*)d_in[2];
    const float* W1 = (const float*)d_in[3];  const float* b1  = (const float*)d_in[4];
    const float* W2 = (const float*)d_in[5];  const float* b2  = (const float*)d_in[6];
    const float* W3 = (const float*)d_in[7];  const float* b3  = (const float*)d_in[8];
    const float* p1 = (const float*)d_in[9];  const float* p2  = (const float*)d_in[10];
    const float* p3 = (const float*)d_in[11];
    const float* L1 = (const float*)d_in[12]; const float* bl1 = (const float*)d_in[13];
    const float* L2 = (const float*)d_in[14]; const float* bl2 = (const float*)d_in[15];
    const float* L3 = (const float*)d_in[16]; const float* bl3 = (const float*)d_in[17];
    float* out = (float*)d_out;

    char* wptr = (char*)d_ws;
    auto alloc = [&](size_t bytes) {
        char* r = wptr;
        wptr += (bytes + 255) & ~(size_t)255;
        return r;
    };
    float* hpre = (float*)alloc(65536ULL * FD * 4);
    float* hbuf = (float*)alloc(65536ULL * FD * 4);
    float* xp2  = (float*)alloc(32768ULL * FD * 4);
    float* xp3  = (float*)alloc(16384ULL * FD * 4);
    float* xp4  = (float*)alloc(8192ULL * FD * 4);
    float* dinv = (float*)alloc(65536ULL * 4);
    int*   nid  = (int*)alloc(65536ULL * 4);
    int*   src1 = (int*)alloc(NE * 4);
    int*   dst1 = (int*)alloc(NE * 4);
    float* ew1  = (float*)alloc(NE * 4);
    int*   src2 = (int*)alloc(NE * 4);
    int*   dst2 = (int*)alloc(NE * 4);
    float* ew2  = (float*)alloc(NE * 4);
    int*   roff = (int*)alloc((size_t)NB * 513 * 4);
    int*   csrc = (int*)alloc((size_t)NE * 4);
    float* ccoef= (float*)alloc((size_t)NE * 4);
    float* r1   = (float*)alloc(128ULL * 256 * 4);
    float* r2   = (float*)alloc(128ULL * 256 * 4);
    float* r3   = (float*)alloc(128ULL * 256 * 4);

    // ---- stage 1 (n_per=512 -> k=256) ----
    gemm128_v2<<<512, 256, 0, stream>>>(x, W1, hpre);
    build_csr<<<NB, 256, 0, stream>>>(src0, dst0, nullptr, 512, dinv, roff, csrc, ccoef);
    agg_csr<<<65536 / 2, 256, 0, stream>>>(hpre, roff, csrc, ccoef, dinv, b1, 9, hbuf);
    pool_kernel<<<NB, 512, 0, stream>>>(hbuf, p1, 512, 256, xp2, nid, r1);
    relabel_kernel<<<NE / 256, 256, 0, stream>>>(src0, dst0, nullptr, nid, src1, dst1, ew1);

    // ---- stage 2 (n_per=256 -> k=128) ----
    gemm128_v2<<<256, 256, 0, stream>>>(xp2, W2, hpre);
    build_csr<<<NB, 256, 0, stream>>>(src1, dst1, ew1, 256, dinv, roff, csrc, ccoef);
    agg_csr<<<32768 / 2, 256, 0, stream>>>(hpre, roff, csrc, ccoef, dinv, b2, 8, hbuf);
    pool_kernel<<<NB, 512, 0, stream>>>(hbuf, p2, 256, 128, xp3, nid, r2);
    relabel_kernel<<<NE / 256, 256, 0, stream>>>(src1, dst1, ew1, nid, src2, dst2, ew2);

    // ---- stage 3 (n_per=128 -> k=64) ----
    gemm128_v2<<<128, 256, 0, stream>>>(xp3, W3, hpre);
    build_csr<<<NB, 256, 0, stream>>>(src2, dst2, ew2, 128, dinv, roff, csrc, ccoef);
    agg_csr<<<16384 / 2, 256, 0, stream>>>(hpre, roff, csrc, ccoef, dinv, b3, 7, hbuf);
    pool_kernel<<<NB, 512, 0, stream>>>(hbuf, p3, 128, 64, xp4, nid, r3);

    // ---- final MLP ----
    mlp_kernel<<<NB, 128, 0, stream>>>(r1, r2, r3, L1, bl1, L2, bl2, L3, bl3, out);
}

// Round 8
// 411.044 us; speedup vs baseline: 2.0080x; 1.0209x over previous
//
#include <hip/hip_runtime.h>
#include <math.h>

#define NB 128          // batch of graphs
#define E_PER 2048
#define NE (NB * E_PER) // 262144 edges
#define FD 128          // feature dim (F_IN = NHID)

// ---------------- GEMM: C[N x 128] = A[N x 128] @ W[128 x 128] (f32) ----------
// 128x128 tile / block, 256 threads, K chunked by 32. LDS ~33 KB -> 4 blocks/CU.
__global__ __launch_bounds__(256) void gemm128_v2(const float* __restrict__ A,
                                                  const float* __restrict__ W,
                                                  float* __restrict__ C) {
    __shared__ float At[32 * 132];   // [k][row], padded stride 132 (16.9 KB)
    __shared__ float Wt[32 * 128];   // [k][col] (16 KB)
    const int tid = threadIdx.x;
    const long rbase = (long)blockIdx.x * 128;
    const int cg = tid & 15;         // col group 0..15
    const int rg = tid >> 4;         // row group 0..15

    float acc[2][2][4][4];
#pragma unroll
    for (int a = 0; a < 2; ++a)
#pragma unroll
        for (int b = 0; b < 2; ++b)
#pragma unroll
            for (int i = 0; i < 4; ++i)
#pragma unroll
                for (int j = 0; j < 4; ++j) acc[a][b][i][j] = 0.f;

    for (int k0 = 0; k0 < 128; k0 += 32) {
        __syncthreads();
#pragma unroll
        for (int q = 0; q < 4; ++q) {
            int idx = tid + 256 * q;          // 0..1023
            int row = idx >> 3, kq = idx & 7; // coalesced: 8 rows x 128B per instr
            float4 a = *(const float4*)&A[(rbase + row) * FD + k0 + kq * 4];
            At[(kq * 4 + 0) * 132 + row] = a.x;
            At[(kq * 4 + 1) * 132 + row] = a.y;
            At[(kq * 4 + 2) * 132 + row] = a.z;
            At[(kq * 4 + 3) * 132 + row] = a.w;
        }
#pragma unroll
        for (int q = 0; q < 4; ++q) {
            int idx = tid + 256 * q;
            int kk = idx >> 5, cq = idx & 31;
            *(float4*)&Wt[kk * 128 + cq * 4] =
                *(const float4*)&W[(k0 + kk) * FD + cq * 4];
        }
        __syncthreads();
#pragma unroll 8
        for (int kk = 0; kk < 32; ++kk) {
            float4 a0 = *(const float4*)&At[kk * 132 + rg * 4];
            float4 a1 = *(const float4*)&At[kk * 132 + 64 + rg * 4];
            float4 b0 = *(const float4*)&Wt[kk * 128 + cg * 4];
            float4 b1 = *(const float4*)&Wt[kk * 128 + 64 + cg * 4];
            float av[2][4] = {{a0.x, a0.y, a0.z, a0.w}, {a1.x, a1.y, a1.z, a1.w}};
            float bv[2][4] = {{b0.x, b0.y, b0.z, b0.w}, {b1.x, b1.y, b1.z, b1.w}};
#pragma unroll
            for (int a = 0; a < 2; ++a)
#pragma unroll
                for (int b = 0; b < 2; ++b)
#pragma unroll
                    for (int i = 0; i < 4; ++i)
#pragma unroll
                        for (int j = 0; j < 4; ++j)
                            acc[a][b][i][j] += av[a][i] * bv[b][j];
        }
    }
#pragma unroll
    for (int a = 0; a < 2; ++a)
#pragma unroll
        for (int i = 0; i < 4; ++i) {
            long row = rbase + a * 64 + rg * 4 + i;
#pragma unroll
            for (int b = 0; b < 2; ++b) {
                float4 o = {acc[a][b][i][0], acc[a][b][i][1],
                            acc[a][b][i][2], acc[a][b][i][3]};
                *(float4*)&C[row * FD + b * 64 + cg * 4] = o;
            }
        }
}

// -------- build per-graph CSR by dst + dinv + edge (src,coef) pairs -----------
__global__ __launch_bounds__(256) void build_csr(const int* __restrict__ src,
                                                 const int* __restrict__ dst,
                                                 const float* __restrict__ ew,
                                                 int n_per,
                                                 float* __restrict__ dinv,
                                                 int* __restrict__ roff,
                                                 float2* __restrict__ cpair) {
    __shared__ int   cnt[512];
    __shared__ int   offs[513];
    __shared__ float dl[512];
    const int g = blockIdx.x, tid = threadIdx.x;
    const int ebase = g * E_PER;
    const int nbase = g * n_per;

    for (int i = tid; i < n_per; i += 256) cnt[i] = 0;
    __syncthreads();
    for (int i = tid; i < E_PER; i += 256) {
        float w = ew ? ew[ebase + i] : 1.0f;
        if (w != 0.f) atomicAdd(&cnt[dst[ebase + i] - nbase], 1);
    }
    __syncthreads();
    for (int i = tid; i < n_per; i += 256) {
        float di = rsqrtf(1.0f + (float)cnt[i]);
        dl[i] = di;
        dinv[nbase + i] = di;
    }
    // exclusive scan: serial on thread 0 (correct; cost negligible at 128 blocks)
    __syncthreads();
    if (tid == 0) {
        int run = 0;
        for (int i = 0; i < n_per; ++i) { offs[i] = run; run += cnt[i]; }
        offs[n_per] = run;
    }
    __syncthreads();
    for (int i = tid; i <= n_per; i += 256)
        roff[g * (n_per + 1) + i] = ebase + offs[i];
    for (int i = tid; i < n_per; i += 256) cnt[i] = offs[i];  // cursors
    __syncthreads();
    for (int i = tid; i < E_PER; i += 256) {
        float w = ew ? ew[ebase + i] : 1.0f;
        if (w != 0.f) {
            int s = src[ebase + i], d = dst[ebase + i];
            int dlo = d - nbase;
            int pos = atomicAdd(&cnt[dlo], 1);
            cpair[ebase + pos] = make_float2(__int_as_float(s), dl[s - nbase] * dl[dlo] * w);
        }
    }
}

// -------- aggregate via CSR gather: hout = relu(sum + self + bias) ------------
// 2 nodes/block, 128 lanes/node. XCD-pinned: graph g -> XCD (g&7) so each
// graph's hpre slice stays in ONE per-XCD L2 (16 graphs x 256KB = 4MB @ stage1).
__global__ __launch_bounds__(256) void agg_csr(const float* __restrict__ hpre,
                                               const int* __restrict__ roff,
                                               const float2* __restrict__ cpair,
                                               const float* __restrict__ dinv,
                                               const float* __restrict__ bias,
                                               int np_shift,
                                               float* __restrict__ hout) {
    const int tid = threadIdx.x;
    const int P = 1 << (np_shift - 1);          // blocks per graph
    const int xcd = blockIdx.x & 7;
    const int idx = blockIdx.x >> 3;
    const int p = idx & (P - 1);
    const int g = ((idx >> (np_shift - 1)) << 3) + xcd;
    const int n_per = 1 << np_shift;
    const int nl = p * 2 + (tid >> 7);
    const int node = g * n_per + nl;
    const int f = tid & 127;
    const int rbase = g * (n_per + 1) + nl;
    const int e0 = roff[rbase], e1 = roff[rbase + 1];
    float acc = 0.f;
    for (int e = e0; e < e1; ++e) {
        float2 pr = cpair[e];
        acc += hpre[(long)__float_as_int(pr.x) * FD + f] * pr.y;
    }
    const float di = dinv[node];
    float v = acc + hpre[(long)node * FD + f] * di * di + bias[f];
    hout[(long)node * FD + f] = fmaxf(v, 0.f);
}

// ------- TopK pool: score, RANK-select (no sort), gather*tanh + readout -------
__global__ __launch_bounds__(512) void pool_kernel(const float* __restrict__ h,
                                                   const float* __restrict__ p,
                                                   int n_per, int k,
                                                   float* __restrict__ xp,
                                                   int* __restrict__ newid,
                                                   float* __restrict__ rout) {
    __shared__ float sc[512];
    __shared__ int   ord[256];   // rank -> local node idx (k <= 256)
    __shared__ float tf[256];    // tanh(score) by rank
    __shared__ float pl[128];
    __shared__ float red[128];
    __shared__ float mxs[512];
    __shared__ float sms[512];
    const int tid = threadIdx.x;
    const int g = blockIdx.x;
    const int nbase = g * n_per;

    if (tid < 128) { float pv = p[tid]; pl[tid] = pv; red[tid] = pv * pv; }
    __syncthreads();
    for (int s = 64; s > 0; s >>= 1) {
        if (tid < s) red[tid] += red[tid + s];
        __syncthreads();
    }
    const float invn = rsqrtf(red[0]);

    // scores: one row per thread
    if (tid < n_per) {
        const float4* hp = (const float4*)&h[(long)(nbase + tid) * FD];
        const float4* pp = (const float4*)pl;
        float a = 0.f;
#pragma unroll
        for (int q = 0; q < 32; ++q) {
            float4 hv = hp[q], pv = pp[q];
            a += hv.x * pv.x + hv.y * pv.y + hv.z * pv.z + hv.w * pv.w;
        }
        sc[tid] = a * invn;
    }
    __syncthreads();

    // rank + scatter (stable desc order == jax.lax.top_k)
    if (tid < n_per) {
        const float si = sc[tid];
        int rank = 0;
        for (int j = 0; j < n_per; ++j) {
            float sj = sc[j];
            rank += (sj > si) || (sj == si && j < tid);
        }
        if (rank < k) {
            ord[rank] = tid;
            tf[rank] = tanhf(si);
            newid[nbase + tid] = g * k + rank;
        } else {
            newid[nbase + tid] = -1;
        }
    }
    __syncthreads();

    // gather + fused [max || mean] readout. f = tid&127 fixed per thread.
    const int f = tid & 127;
    const int grp = tid >> 7;    // 0..3
    float mx = -INFINITY, sm = 0.f;
    for (int t = tid; t < k * FD; t += 512) {
        int r = t >> 7;
        float val = h[(long)(nbase + ord[r]) * FD + f] * tf[r];
        xp[((long)g * k + r) * FD + f] = val;
        mx = fmaxf(mx, val);
        sm += val;
    }
    mxs[grp * 128 + f] = mx;
    sms[grp * 128 + f] = sm;
    __syncthreads();
    if (tid < 128) {
        float m0 = fmaxf(fmaxf(mxs[f], mxs[128 + f]), fmaxf(mxs[256 + f], mxs[384 + f]));
        float s0 = sms[f] + sms[128 + f] + sms[256 + f] + sms[384 + f];
        rout[g * 256 + f] = m0;
        rout[g * 256 + 128 + f] = s0 / (float)k;
    }
}

// ---------------- edge relabel + mask ------------------------------------------
__global__ __launch_bounds__(256) void relabel_kernel(const int* __restrict__ src,
                                                      const int* __restrict__ dst,
                                                      const float* __restrict__ ew,
                                                      const int* __restrict__ newid,
                                                      int* __restrict__ nsrc,
                                                      int* __restrict__ ndst,
                                                      float* __restrict__ new_ew) {
    const int e = blockIdx.x * 256 + threadIdx.x;
    int s = src[e], d = dst[e];
    float w = ew ? ew[e] : 1.0f;
    int ns = newid[s], nd = newid[d];
    bool keep = (ns >= 0) && (nd >= 0);
    nsrc[e] = ns > 0 ? ns : 0;
    ndst[e] = nd > 0 ? nd : 0;
    new_ew[e] = keep ? w : 0.f;
}

// ---------------- final MLP + log_softmax --------------------------------------
__global__ __launch_bounds__(128) void mlp_kernel(const float* __restrict__ r1,
                                                  const float* __restrict__ r2,
                                                  const float* __restrict__ r3,
                                                  const float* __restrict__ L1,
                                                  const float* __restrict__ bl1,
                                                  const float* __restrict__ L2,
                                                  const float* __restrict__ bl2,
                                                  const float* __restrict__ L3,
                                                  const float* __restrict__ bl3,
                                                  float* __restrict__ out) {
    __shared__ float z[256], z1[128], z2[64];
    const int g = blockIdx.x, tid = threadIdx.x;
    for (int t = tid; t < 256; t += 128)
        z[t] = r1[g * 256 + t] + r2[g * 256 + t] + r3[g * 256 + t];
    __syncthreads();
    {
        float a = bl1[tid];
        for (int i = 0; i < 256; ++i) a += z[i] * L1[i * 128 + tid];
        z1[tid] = fmaxf(a, 0.f);
    }
    __syncthreads();
    if (tid < 64) {
        float a = bl2[tid];
        for (int i = 0; i < 128; ++i) a += z1[i] * L2[i * 64 + tid];
        z2[tid] = fmaxf(a, 0.f);
    }
    __syncthreads();
    if (tid == 0) {
        float l0 = bl3[0], l1v = bl3[1];
        for (int i = 0; i < 64; ++i) {
            l0  += z2[i] * L3[i * 2 + 0];
            l1v += z2[i] * L3[i * 2 + 1];
        }
        float m = fmaxf(l0, l1v);
        float lse = m + logf(expf(l0 - m) + expf(l1v - m));
        out[g * 2 + 0] = l0 - lse;
        out[g * 2 + 1] = l1v - lse;
    }
}

extern "C" void kernel_launch(void* const* d_in, const int* in_sizes, int n_in,
                              void* d_out, int out_size, void* d_ws, size_t ws_size,
                              hipStream_t stream) {
    const float* x   = (const float*)d_in[0];
    const int*  src0 = (const int*)d_in[1];
    const int*  dst0 = (const int*)d_in[2];
    const float* W1 = (const float*)d_in[3];  const float* b1  = (const float*)d_in[4];
    const float* W2 = (const float*)d_in[5];  const float* b2  = (const float*)d_in[6];
    const float* W3 = (const float*)d_in[7];  const float* b3  = (const float*)d_in[8];
    const float* p1 = (const float*)d_in[9];  const float* p2  = (const float*)d_in[10];
    const float* p3 = (const float*)d_in[11];
    const float* L1 = (const float*)d_in[12]; const float* bl1 = (const float*)d_in[13];
    const float* L2 = (const float*)d_in[14]; const float* bl2 = (const float*)d_in[15];
    const float* L3 = (const float*)d_in[16]; const float* bl3 = (const float*)d_in[17];
    float* out = (float*)d_out;

    char* wptr = (char*)d_ws;
    auto alloc = [&](size_t bytes) {
        char* r = wptr;
        wptr += (bytes + 255) & ~(size_t)255;
        return r;
    };
    float* hpre = (float*)alloc(65536ULL * FD * 4);
    float* hbuf = (float*)alloc(65536ULL * FD * 4);
    float* xp2  = (float*)alloc(32768ULL * FD * 4);
    float* xp3  = (float*)alloc(16384ULL * FD * 4);
    float* xp4  = (float*)alloc(8192ULL * FD * 4);
    float* dinv = (float*)alloc(65536ULL * 4);
    int*   nid  = (int*)alloc(65536ULL * 4);
    int*   src1 = (int*)alloc(NE * 4);
    int*   dst1 = (int*)alloc(NE * 4);
    float* ew1  = (float*)alloc(NE * 4);
    int*   src2 = (int*)alloc(NE * 4);
    int*   dst2 = (int*)alloc(NE * 4);
    float* ew2  = (float*)alloc(NE * 4);
    int*   roff = (int*)alloc((size_t)NB * 513 * 4);
    float2* cpair = (float2*)alloc((size_t)NE * 8);
    float* r1   = (float*)alloc(128ULL * 256 * 4);
    float* r2   = (float*)alloc(128ULL * 256 * 4);
    float* r3   = (float*)alloc(128ULL * 256 * 4);

    // ---- stage 1 (n_per=512 -> k=256) ----
    gemm128_v2<<<512, 256, 0, stream>>>(x, W1, hpre);
    build_csr<<<NB, 256, 0, stream>>>(src0, dst0, nullptr, 512, dinv, roff, cpair);
    agg_csr<<<65536 / 2, 256, 0, stream>>>(hpre, roff, cpair, dinv, b1, 9, hbuf);
    pool_kernel<<<NB, 512, 0, stream>>>(hbuf, p1, 512, 256, xp2, nid, r1);
    relabel_kernel<<<NE / 256, 256, 0, stream>>>(src0, dst0, nullptr, nid, src1, dst1, ew1);

    // ---- stage 2 (n_per=256 -> k=128) ----
    gemm128_v2<<<256, 256, 0, stream>>>(xp2, W2, hpre);
    build_csr<<<NB, 256, 0, stream>>>(src1, dst1, ew1, 256, dinv, roff, cpair);
    agg_csr<<<32768 / 2, 256, 0, stream>>>(hpre, roff, cpair, dinv, b2, 8, hbuf);
    pool_kernel<<<NB, 512, 0, stream>>>(hbuf, p2, 256, 128, xp3, nid, r2);
    relabel_kernel<<<NE / 256, 256, 0, stream>>>(src1, dst1, ew1, nid, src2, dst2, ew2);

    // ---- stage 3 (n_per=128 -> k=64) ----
    gemm128_v2<<<128, 256, 0, stream>>>(xp3, W3, hpre);
    build_csr<<<NB, 256, 0, stream>>>(src2, dst2, ew2, 128, dinv, roff, cpair);
    agg_csr<<<16384 / 2, 256, 0, stream>>>(hpre, roff, cpair, dinv, b3, 7, hbuf);
    pool_kernel<<<NB, 512, 0, stream>>>(hbuf, p3, 128, 64, xp4, nid, r3);

    // ---- final MLP ----
    mlp_kernel<<<NB, 128, 0, stream>>>(r1, r2, r3, L1, bl1, L2, bl2, L3, bl3, out);
}

// Round 9
// 383.071 us; speedup vs baseline: 2.1546x; 1.0730x over previous
//
#include <hip/hip_runtime.h>
#include <math.h>

#define NB 128          // batch of graphs
#define E_PER 2048
#define NE (NB * E_PER) // 262144 edges
#define FD 128          // feature dim (F_IN = NHID)

// ---------------- GEMM: C[N x 128] = A[N x 128] @ W[128 x 128] (f32) ----------
// 128x128 tile / block, 256 threads, K chunked by 32. LDS ~33 KB -> 4 blocks/CU.
// Tile index swizzled so tile's graph lands on XCD (graph&7) == consumer kernels.
// swz_shift S: tiles per graph = 1<<S. orig = ((q>>S)<<(3+S)) | (xcd<<S) | (q&(2^S-1)).
__global__ __launch_bounds__(256) void gemm128_v2(const float* __restrict__ A,
                                                  const float* __restrict__ W,
                                                  float* __restrict__ C,
                                                  int swz_shift) {
    const int bid = blockIdx.x;
    const int xcd = bid & 7;
    const int q = bid >> 3;
    const int S = swz_shift;
    const int tile = ((q >> S) << (3 + S)) | (xcd << S) | (q & ((1 << S) - 1));

    __shared__ float At[32 * 132];   // [k][row], padded stride 132 (16.9 KB)
    __shared__ float Wt[32 * 128];   // [k][col] (16 KB)
    const int tid = threadIdx.x;
    const long rbase = (long)tile * 128;
    const int cg = tid & 15;         // col group 0..15
    const int rg = tid >> 4;         // row group 0..15

    float acc[2][2][4][4];
#pragma unroll
    for (int a = 0; a < 2; ++a)
#pragma unroll
        for (int b = 0; b < 2; ++b)
#pragma unroll
            for (int i = 0; i < 4; ++i)
#pragma unroll
                for (int j = 0; j < 4; ++j) acc[a][b][i][j] = 0.f;

    for (int k0 = 0; k0 < 128; k0 += 32) {
        __syncthreads();
#pragma unroll
        for (int qq = 0; qq < 4; ++qq) {
            int idx = tid + 256 * qq;         // 0..1023
            int row = idx >> 3, kq = idx & 7; // coalesced: 8 rows x 128B per instr
            float4 a = *(const float4*)&A[(rbase + row) * FD + k0 + kq * 4];
            At[(kq * 4 + 0) * 132 + row] = a.x;
            At[(kq * 4 + 1) * 132 + row] = a.y;
            At[(kq * 4 + 2) * 132 + row] = a.z;
            At[(kq * 4 + 3) * 132 + row] = a.w;
        }
#pragma unroll
        for (int qq = 0; qq < 4; ++qq) {
            int idx = tid + 256 * qq;
            int kk = idx >> 5, cq = idx & 31;
            *(float4*)&Wt[kk * 128 + cq * 4] =
                *(const float4*)&W[(k0 + kk) * FD + cq * 4];
        }
        __syncthreads();
#pragma unroll 8
        for (int kk = 0; kk < 32; ++kk) {
            float4 a0 = *(const float4*)&At[kk * 132 + rg * 4];
            float4 a1 = *(const float4*)&At[kk * 132 + 64 + rg * 4];
            float4 b0 = *(const float4*)&Wt[kk * 128 + cg * 4];
            float4 b1 = *(const float4*)&Wt[kk * 128 + 64 + cg * 4];
            float av[2][4] = {{a0.x, a0.y, a0.z, a0.w}, {a1.x, a1.y, a1.z, a1.w}};
            float bv[2][4] = {{b0.x, b0.y, b0.z, b0.w}, {b1.x, b1.y, b1.z, b1.w}};
#pragma unroll
            for (int a = 0; a < 2; ++a)
#pragma unroll
                for (int b = 0; b < 2; ++b)
#pragma unroll
                    for (int i = 0; i < 4; ++i)
#pragma unroll
                        for (int j = 0; j < 4; ++j)
                            acc[a][b][i][j] += av[a][i] * bv[b][j];
        }
    }
#pragma unroll
    for (int a = 0; a < 2; ++a)
#pragma unroll
        for (int i = 0; i < 4; ++i) {
            long row = rbase + a * 64 + rg * 4 + i;
#pragma unroll
            for (int b = 0; b < 2; ++b) {
                float4 o = {acc[a][b][i][0], acc[a][b][i][1],
                            acc[a][b][i][2], acc[a][b][i][3]};
                *(float4*)&C[row * FD + b * 64 + cg * 4] = o;
            }
        }
}

// -------- build per-graph CSR by dst + dinv + edge (src,coef) pairs -----------
__global__ __launch_bounds__(256) void build_csr(const int* __restrict__ src,
                                                 const int* __restrict__ dst,
                                                 const float* __restrict__ ew,
                                                 int n_per,
                                                 float* __restrict__ dinv,
                                                 int* __restrict__ roff,
                                                 float2* __restrict__ cpair) {
    __shared__ int   cnt[512];
    __shared__ int   offs[513];
    __shared__ float dl[512];
    const int g = blockIdx.x, tid = threadIdx.x;
    const int ebase = g * E_PER;
    const int nbase = g * n_per;

    for (int i = tid; i < n_per; i += 256) cnt[i] = 0;
    __syncthreads();
    for (int i = tid; i < E_PER; i += 256) {
        float w = ew ? ew[ebase + i] : 1.0f;
        if (w != 0.f) atomicAdd(&cnt[dst[ebase + i] - nbase], 1);
    }
    __syncthreads();
    for (int i = tid; i < n_per; i += 256) {
        float di = rsqrtf(1.0f + (float)cnt[i]);
        dl[i] = di;
        dinv[nbase + i] = di;
    }
    // exclusive scan: serial on thread 0 (correct; cost negligible at 128 blocks)
    __syncthreads();
    if (tid == 0) {
        int run = 0;
        for (int i = 0; i < n_per; ++i) { offs[i] = run; run += cnt[i]; }
        offs[n_per] = run;
    }
    __syncthreads();
    for (int i = tid; i <= n_per; i += 256)
        roff[g * (n_per + 1) + i] = ebase + offs[i];
    for (int i = tid; i < n_per; i += 256) cnt[i] = offs[i];  // cursors
    __syncthreads();
    for (int i = tid; i < E_PER; i += 256) {
        float w = ew ? ew[ebase + i] : 1.0f;
        if (w != 0.f) {
            int s = src[ebase + i], d = dst[ebase + i];
            int dlo = d - nbase;
            int pos = atomicAdd(&cnt[dlo], 1);
            cpair[ebase + pos] = make_float2(__int_as_float(s), dl[s - nbase] * dl[dlo] * w);
        }
    }
}

// -------- aggregate via CSR gather: hout = relu(sum + self + bias) ------------
// 2 nodes/block, 128 lanes/node. XCD-pinned: graph g -> XCD (g&7).
// Edge loop 4-wide software-pipelined for memory-level parallelism.
__global__ __launch_bounds__(256) void agg_csr(const float* __restrict__ hpre,
                                               const int* __restrict__ roff,
                                               const float2* __restrict__ cpair,
                                               const float* __restrict__ dinv,
                                               const float* __restrict__ bias,
                                               int np_shift,
                                               float* __restrict__ hout) {
    const int tid = threadIdx.x;
    const int P = 1 << (np_shift - 1);          // blocks per graph
    const int xcd = blockIdx.x & 7;
    const int idx = blockIdx.x >> 3;
    const int p = idx & (P - 1);
    const int g = ((idx >> (np_shift - 1)) << 3) + xcd;
    const int n_per = 1 << np_shift;
    const int nl = p * 2 + (tid >> 7);
    const int node = g * n_per + nl;
    const int f = tid & 127;
    const int rbase = g * (n_per + 1) + nl;
    const int e0 = roff[rbase], e1 = roff[rbase + 1];
    const float selfh = hpre[(long)node * FD + f];
    float acc = 0.f;
    int e = e0, n = e1 - e0;
    while (n >= 4) {
        float2 p0 = cpair[e], p1 = cpair[e + 1], p2 = cpair[e + 2], p3 = cpair[e + 3];
        float h0 = hpre[(long)__float_as_int(p0.x) * FD + f];
        float h1 = hpre[(long)__float_as_int(p1.x) * FD + f];
        float h2 = hpre[(long)__float_as_int(p2.x) * FD + f];
        float h3 = hpre[(long)__float_as_int(p3.x) * FD + f];
        acc += h0 * p0.y + h1 * p1.y + h2 * p2.y + h3 * p3.y;
        e += 4; n -= 4;
    }
    while (n > 0) {
        float2 pr = cpair[e];
        acc += hpre[(long)__float_as_int(pr.x) * FD + f] * pr.y;
        ++e; --n;
    }
    const float di = dinv[node];
    float v = acc + selfh * di * di + bias[f];
    hout[(long)node * FD + f] = fmaxf(v, 0.f);
}

// ------- TopK pool: score, RANK-select (no sort), gather*tanh + readout -------
__global__ __launch_bounds__(512) void pool_kernel(const float* __restrict__ h,
                                                   const float* __restrict__ p,
                                                   int n_per, int k,
                                                   float* __restrict__ xp,
                                                   int* __restrict__ newid,
                                                   float* __restrict__ rout) {
    __shared__ float sc[512];
    __shared__ int   ord[256];   // rank -> local node idx (k <= 256)
    __shared__ float tf[256];    // tanh(score) by rank
    __shared__ float pl[128];
    __shared__ float red[128];
    __shared__ float mxs[512];
    __shared__ float sms[512];
    const int tid = threadIdx.x;
    const int g = blockIdx.x;
    const int nbase = g * n_per;

    if (tid < 128) { float pv = p[tid]; pl[tid] = pv; red[tid] = pv * pv; }
    __syncthreads();
    for (int s = 64; s > 0; s >>= 1) {
        if (tid < s) red[tid] += red[tid + s];
        __syncthreads();
    }
    const float invn = rsqrtf(red[0]);

    // scores: one row per thread
    if (tid < n_per) {
        const float4* hp = (const float4*)&h[(long)(nbase + tid) * FD];
        const float4* pp = (const float4*)pl;
        float a = 0.f;
#pragma unroll
        for (int q = 0; q < 32; ++q) {
            float4 hv = hp[q], pv = pp[q];
            a += hv.x * pv.x + hv.y * pv.y + hv.z * pv.z + hv.w * pv.w;
        }
        sc[tid] = a * invn;
    }
    __syncthreads();

    // rank + scatter (stable desc order == jax.lax.top_k)
    if (tid < n_per) {
        const float si = sc[tid];
        int rank = 0;
        for (int j = 0; j < n_per; ++j) {
            float sj = sc[j];
            rank += (sj > si) || (sj == si && j < tid);
        }
        if (rank < k) {
            ord[rank] = tid;
            tf[rank] = tanhf(si);
            newid[nbase + tid] = g * k + rank;
        } else {
            newid[nbase + tid] = -1;
        }
    }
    __syncthreads();

    // gather + fused [max || mean] readout. f = tid&127 fixed per thread.
    const int f = tid & 127;
    const int grp = tid >> 7;    // 0..3
    float mx = -INFINITY, sm = 0.f;
    for (int t = tid; t < k * FD; t += 512) {
        int r = t >> 7;
        float val = h[(long)(nbase + ord[r]) * FD + f] * tf[r];
        xp[((long)g * k + r) * FD + f] = val;
        mx = fmaxf(mx, val);
        sm += val;
    }
    mxs[grp * 128 + f] = mx;
    sms[grp * 128 + f] = sm;
    __syncthreads();
    if (tid < 128) {
        float m0 = fmaxf(fmaxf(mxs[f], mxs[128 + f]), fmaxf(mxs[256 + f], mxs[384 + f]));
        float s0 = sms[f] + sms[128 + f] + sms[256 + f] + sms[384 + f];
        rout[g * 256 + f] = m0;
        rout[g * 256 + 128 + f] = s0 / (float)k;
    }
}

// ---------------- edge relabel + mask ------------------------------------------
__global__ __launch_bounds__(256) void relabel_kernel(const int* __restrict__ src,
                                                      const int* __restrict__ dst,
                                                      const float* __restrict__ ew,
                                                      const int* __restrict__ newid,
                                                      int* __restrict__ nsrc,
                                                      int* __restrict__ ndst,
                                                      float* __restrict__ new_ew) {
    const int e = blockIdx.x * 256 + threadIdx.x;
    int s = src[e], d = dst[e];
    float w = ew ? ew[e] : 1.0f;
    int ns = newid[s], nd = newid[d];
    bool keep = (ns >= 0) && (nd >= 0);
    nsrc[e] = ns > 0 ? ns : 0;
    ndst[e] = nd > 0 ? nd : 0;
    new_ew[e] = keep ? w : 0.f;
}

// ---------------- final MLP + log_softmax --------------------------------------
__global__ __launch_bounds__(128) void mlp_kernel(const float* __restrict__ r1,
                                                  const float* __restrict__ r2,
                                                  const float* __restrict__ r3,
                                                  const float* __restrict__ L1,
                                                  const float* __restrict__ bl1,
                                                  const float* __restrict__ L2,
                                                  const float* __restrict__ bl2,
                                                  const float* __restrict__ L3,
                                                  const float* __restrict__ bl3,
                                                  float* __restrict__ out) {
    __shared__ float z[256], z1[128], z2[64];
    const int g = blockIdx.x, tid = threadIdx.x;
    for (int t = tid; t < 256; t += 128)
        z[t] = r1[g * 256 + t] + r2[g * 256 + t] + r3[g * 256 + t];
    __syncthreads();
    {
        float a = bl1[tid];
        for (int i = 0; i < 256; ++i) a += z[i] * L1[i * 128 + tid];
        z1[tid] = fmaxf(a, 0.f);
    }
    __syncthreads();
    if (tid < 64) {
        float a = bl2[tid];
        for (int i = 0; i < 128; ++i) a += z1[i] * L2[i * 64 + tid];
        z2[tid] = fmaxf(a, 0.f);
    }
    __syncthreads();
    if (tid == 0) {
        float l0 = bl3[0], l1v = bl3[1];
        for (int i = 0; i < 64; ++i) {
            l0  += z2[i] * L3[i * 2 + 0];
            l1v += z2[i] * L3[i * 2 + 1];
        }
        float m = fmaxf(l0, l1v);
        float lse = m + logf(expf(l0 - m) + expf(l1v - m));
        out[g * 2 + 0] = l0 - lse;
        out[g * 2 + 1] = l1v - lse;
    }
}

extern "C" void kernel_launch(void* const* d_in, const int* in_sizes, int n_in,
                              void* d_out, int out_size, void* d_ws, size_t ws_size,
                              hipStream_t stream) {
    const float* x   = (const float*)d_in[0];
    const int*  src0 = (const int*)d_in[1];
    const int*  dst0 = (const int*)d_in[2];
    const float* W1 = (const float*)d_in[3];  const float* b1  = (const float*)d_in[4];
    const float* W2 = (const float*)d_in[5];  const float* b2  = (const float*)d_in[6];
    const float* W3 = (const float*)d_in[7];  const float* b3  = (const float*)d_in[8];
    const float* p1 = (const float*)d_in[9];  const float* p2  = (const float*)d_in[10];
    const float* p3 = (const float*)d_in[11];
    const float* L1 = (const float*)d_in[12]; const float* bl1 = (const float*)d_in[13];
    const float* L2 = (const float*)d_in[14]; const float* bl2 = (const float*)d_in[15];
    const float* L3 = (const float*)d_in[16]; const float* bl3 = (const float*)d_in[17];
    float* out = (float*)d_out;

    char* wptr = (char*)d_ws;
    auto alloc = [&](size_t bytes) {
        char* r = wptr;
        wptr += (bytes + 255) & ~(size_t)255;
        return r;
    };
    float* hpre = (float*)alloc(65536ULL * FD * 4);
    float* hbuf = (float*)alloc(65536ULL * FD * 4);
    float* xp2  = (float*)alloc(32768ULL * FD * 4);
    float* xp3  = (float*)alloc(16384ULL * FD * 4);
    float* xp4  = (float*)alloc(8192ULL * FD * 4);
    float* dinv = (float*)alloc(65536ULL * 4);
    int*   nid  = (int*)alloc(65536ULL * 4);
    int*   src1 = (int*)alloc(NE * 4);
    int*   dst1 = (int*)alloc(NE * 4);
    float* ew1  = (float*)alloc(NE * 4);
    int*   src2 = (int*)alloc(NE * 4);
    int*   dst2 = (int*)alloc(NE * 4);
    float* ew2  = (float*)alloc(NE * 4);
    int*   roff = (int*)alloc((size_t)NB * 513 * 4);
    float2* cpair = (float2*)alloc((size_t)NE * 8);
    float* r1   = (float*)alloc(128ULL * 256 * 4);
    float* r2   = (float*)alloc(128ULL * 256 * 4);
    float* r3   = (float*)alloc(128ULL * 256 * 4);

    // ---- stage 1 (n_per=512 -> k=256): 4 tiles/graph -> S=2 ----
    gemm128_v2<<<512, 256, 0, stream>>>(x, W1, hpre, 2);
    build_csr<<<NB, 256, 0, stream>>>(src0, dst0, nullptr, 512, dinv, roff, cpair);
    agg_csr<<<65536 / 2, 256, 0, stream>>>(hpre, roff, cpair, dinv, b1, 9, hbuf);
    pool_kernel<<<NB, 512, 0, stream>>>(hbuf, p1, 512, 256, xp2, nid, r1);
    relabel_kernel<<<NE / 256, 256, 0, stream>>>(src0, dst0, nullptr, nid, src1, dst1, ew1);

    // ---- stage 2 (n_per=256 -> k=128): 2 tiles/graph -> S=1 ----
    gemm128_v2<<<256, 256, 0, stream>>>(xp2, W2, hpre, 1);
    build_csr<<<NB, 256, 0, stream>>>(src1, dst1, ew1, 256, dinv, roff, cpair);
    agg_csr<<<32768 / 2, 256, 0, stream>>>(hpre, roff, cpair, dinv, b2, 8, hbuf);
    pool_kernel<<<NB, 512, 0, stream>>>(hbuf, p2, 256, 128, xp3, nid, r2);
    relabel_kernel<<<NE / 256, 256, 0, stream>>>(src1, dst1, ew1, nid, src2, dst2, ew2);

    // ---- stage 3 (n_per=128 -> k=64): 1 tile/graph -> S=0 ----
    gemm128_v2<<<128, 256, 0, stream>>>(xp3, W3, hpre, 0);
    build_csr<<<NB, 256, 0, stream>>>(src2, dst2, ew2, 128, dinv, roff, cpair);
    agg_csr<<<16384 / 2, 256, 0, stream>>>(hpre, roff, cpair, dinv, b3, 7, hbuf);
    pool_kernel<<<NB, 512, 0, stream>>>(hbuf, p3, 128, 64, xp4, nid, r3);

    // ---- final MLP ----
    mlp_kernel<<<NB, 128, 0, stream>>>(r1, r2, r3, L1, bl1, L2, bl2, L3, bl3, out);
}

// Round 10
// 379.904 us; speedup vs baseline: 2.1726x; 1.0083x over previous
//
#include <hip/hip_runtime.h>
#include <math.h>

#define NB 128          // batch of graphs
#define E_PER 2048
#define NE (NB * E_PER) // 262144 edges
#define FD 128          // feature dim (F_IN = NHID)

// ---------------- GEMM: C[N x 128] = A[N x 128] @ W[128 x 128] (f32) ----------
// 128x128 tile / block, 256 threads, K chunked by 32. LDS ~33 KB -> 4 blocks/CU.
// Tile index swizzled so tile's graph lands on XCD (graph&7) == consumer kernels.
__global__ __launch_bounds__(256) void gemm128_v2(const float* __restrict__ A,
                                                  const float* __restrict__ W,
                                                  float* __restrict__ C,
                                                  int swz_shift) {
    const int bid = blockIdx.x;
    const int xcd = bid & 7;
    const int q = bid >> 3;
    const int S = swz_shift;
    const int tile = ((q >> S) << (3 + S)) | (xcd << S) | (q & ((1 << S) - 1));

    __shared__ float At[32 * 132];   // [k][row], padded stride 132 (16.9 KB)
    __shared__ float Wt[32 * 128];   // [k][col] (16 KB)
    const int tid = threadIdx.x;
    const long rbase = (long)tile * 128;
    const int cg = tid & 15;         // col group 0..15
    const int rg = tid >> 4;         // row group 0..15

    float acc[2][2][4][4];
#pragma unroll
    for (int a = 0; a < 2; ++a)
#pragma unroll
        for (int b = 0; b < 2; ++b)
#pragma unroll
            for (int i = 0; i < 4; ++i)
#pragma unroll
                for (int j = 0; j < 4; ++j) acc[a][b][i][j] = 0.f;

    for (int k0 = 0; k0 < 128; k0 += 32) {
        __syncthreads();
#pragma unroll
        for (int qq = 0; qq < 4; ++qq) {
            int idx = tid + 256 * qq;         // 0..1023
            int row = idx >> 3, kq = idx & 7; // coalesced: 8 rows x 128B per instr
            float4 a = *(const float4*)&A[(rbase + row) * FD + k0 + kq * 4];
            At[(kq * 4 + 0) * 132 + row] = a.x;
            At[(kq * 4 + 1) * 132 + row] = a.y;
            At[(kq * 4 + 2) * 132 + row] = a.z;
            At[(kq * 4 + 3) * 132 + row] = a.w;
        }
#pragma unroll
        for (int qq = 0; qq < 4; ++qq) {
            int idx = tid + 256 * qq;
            int kk = idx >> 5, cq = idx & 31;
            *(float4*)&Wt[kk * 128 + cq * 4] =
                *(const float4*)&W[(k0 + kk) * FD + cq * 4];
        }
        __syncthreads();
#pragma unroll 8
        for (int kk = 0; kk < 32; ++kk) {
            float4 a0 = *(const float4*)&At[kk * 132 + rg * 4];
            float4 a1 = *(const float4*)&At[kk * 132 + 64 + rg * 4];
            float4 b0 = *(const float4*)&Wt[kk * 128 + cg * 4];
            float4 b1 = *(const float4*)&Wt[kk * 128 + 64 + cg * 4];
            float av[2][4] = {{a0.x, a0.y, a0.z, a0.w}, {a1.x, a1.y, a1.z, a1.w}};
            float bv[2][4] = {{b0.x, b0.y, b0.z, b0.w}, {b1.x, b1.y, b1.z, b1.w}};
#pragma unroll
            for (int a = 0; a < 2; ++a)
#pragma unroll
                for (int b = 0; b < 2; ++b)
#pragma unroll
                    for (int i = 0; i < 4; ++i)
#pragma unroll
                        for (int j = 0; j < 4; ++j)
                            acc[a][b][i][j] += av[a][i] * bv[b][j];
        }
    }
#pragma unroll
    for (int a = 0; a < 2; ++a)
#pragma unroll
        for (int i = 0; i < 4; ++i) {
            long row = rbase + a * 64 + rg * 4 + i;
#pragma unroll
            for (int b = 0; b < 2; ++b) {
                float4 o = {acc[a][b][i][0], acc[a][b][i][1],
                            acc[a][b][i][2], acc[a][b][i][3]};
                *(float4*)&C[row * FD + b * 64 + cg * 4] = o;
            }
        }
}

// -------- build per-graph CSR by dst + dinv + edge (src,coef) pairs -----------
__global__ __launch_bounds__(256) void build_csr(const int* __restrict__ src,
                                                 const int* __restrict__ dst,
                                                 const float* __restrict__ ew,
                                                 int n_per,
                                                 float* __restrict__ dinv,
                                                 int* __restrict__ roff,
                                                 float2* __restrict__ cpair) {
    __shared__ int   cnt[512];
    __shared__ int   offs[513];
    __shared__ float dl[512];
    const int g = blockIdx.x, tid = threadIdx.x;
    const int ebase = g * E_PER;
    const int nbase = g * n_per;

    for (int i = tid; i < n_per; i += 256) cnt[i] = 0;
    __syncthreads();
    for (int i = tid; i < E_PER; i += 256) {
        float w = ew ? ew[ebase + i] : 1.0f;
        if (w != 0.f) atomicAdd(&cnt[dst[ebase + i] - nbase], 1);
    }
    __syncthreads();
    for (int i = tid; i < n_per; i += 256) {
        float di = rsqrtf(1.0f + (float)cnt[i]);
        dl[i] = di;
        dinv[nbase + i] = di;
    }
    // exclusive scan: serial on thread 0 (correct; cost negligible at 128 blocks)
    __syncthreads();
    if (tid == 0) {
        int run = 0;
        for (int i = 0; i < n_per; ++i) { offs[i] = run; run += cnt[i]; }
        offs[n_per] = run;
    }
    __syncthreads();
    for (int i = tid; i <= n_per; i += 256)
        roff[g * (n_per + 1) + i] = ebase + offs[i];
    for (int i = tid; i < n_per; i += 256) cnt[i] = offs[i];  // cursors
    __syncthreads();
    for (int i = tid; i < E_PER; i += 256) {
        float w = ew ? ew[ebase + i] : 1.0f;
        if (w != 0.f) {
            int s = src[ebase + i], d = dst[ebase + i];
            int dlo = d - nbase;
            int pos = atomicAdd(&cnt[dlo], 1);
            cpair[ebase + pos] = make_float2(__int_as_float(s), dl[s - nbase] * dl[dlo] * w);
        }
    }
}

// -------- aggregate via CSR gather + FUSED raw pool-score ---------------------
// hout = relu(sum + self + bias); scraw[node] = dot(hout[node], p)  (unscaled)
// 2 nodes/block, 128 lanes/node (= 2 waves). XCD-pinned: graph g -> XCD (g&7).
__global__ __launch_bounds__(256) void agg_csr(const float* __restrict__ hpre,
                                               const int* __restrict__ roff,
                                               const float2* __restrict__ cpair,
                                               const float* __restrict__ dinv,
                                               const float* __restrict__ bias,
                                               const float* __restrict__ pvec,
                                               int np_shift,
                                               float* __restrict__ hout,
                                               float* __restrict__ scraw) {
    __shared__ float part[4];
    const int tid = threadIdx.x;
    const int P = 1 << (np_shift - 1);          // blocks per graph
    const int xcd = blockIdx.x & 7;
    const int idx = blockIdx.x >> 3;
    const int p = idx & (P - 1);
    const int g = ((idx >> (np_shift - 1)) << 3) + xcd;
    const int n_per = 1 << np_shift;
    const int nl = p * 2 + (tid >> 7);
    const int node = g * n_per + nl;
    const int f = tid & 127;
    const int rbase = g * (n_per + 1) + nl;
    const int e0 = roff[rbase], e1 = roff[rbase + 1];
    const float selfh = hpre[(long)node * FD + f];
    float acc = 0.f;
    int e = e0, n = e1 - e0;
    while (n >= 4) {
        float2 p0 = cpair[e], p1 = cpair[e + 1], p2 = cpair[e + 2], p3 = cpair[e + 3];
        float h0 = hpre[(long)__float_as_int(p0.x) * FD + f];
        float h1 = hpre[(long)__float_as_int(p1.x) * FD + f];
        float h2 = hpre[(long)__float_as_int(p2.x) * FD + f];
        float h3 = hpre[(long)__float_as_int(p3.x) * FD + f];
        acc += h0 * p0.y + h1 * p1.y + h2 * p2.y + h3 * p3.y;
        e += 4; n -= 4;
    }
    while (n > 0) {
        float2 pr = cpair[e];
        acc += hpre[(long)__float_as_int(pr.x) * FD + f] * pr.y;
        ++e; --n;
    }
    const float di = dinv[node];
    float v = fmaxf(acc + selfh * di * di + bias[f], 0.f);
    hout[(long)node * FD + f] = v;

    // fused raw score: wave-reduce v*p[f] over 64 lanes, combine 2 waves in LDS
    float pr = v * pvec[f];
#pragma unroll
    for (int o = 32; o > 0; o >>= 1) pr += __shfl_down(pr, o);
    if ((tid & 63) == 0) part[tid >> 6] = pr;
    __syncthreads();
    if (tid == 0)   scraw[node]     = part[0] + part[1];
    if (tid == 128) scraw[node]     = part[2] + part[3];
}

// ------- TopK pool: rank-select on precomputed scores, gather*tanh + readout --
__global__ __launch_bounds__(512) void pool_kernel(const float* __restrict__ h,
                                                   const float* __restrict__ scraw,
                                                   const float* __restrict__ p,
                                                   int n_per, int k,
                                                   float* __restrict__ xp,
                                                   int* __restrict__ newid,
                                                   float* __restrict__ rout) {
    __shared__ float sc[512];
    __shared__ int   ord[256];   // rank -> local node idx (k <= 256)
    __shared__ float tf[256];    // tanh(score) by rank
    __shared__ float red[128];
    __shared__ float mxs[512];
    __shared__ float sms[512];
    const int tid = threadIdx.x;
    const int g = blockIdx.x;
    const int nbase = g * n_per;

    if (tid < 128) { float pv = p[tid]; red[tid] = pv * pv; }
    __syncthreads();
    for (int s = 64; s > 0; s >>= 1) {
        if (tid < s) red[tid] += red[tid + s];
        __syncthreads();
    }
    const float invn = rsqrtf(red[0]);

    // scores: precomputed raw dots (coalesced 2KB read), scale by 1/||p||
    if (tid < n_per) sc[tid] = scraw[nbase + tid] * invn;
    __syncthreads();

    // rank + scatter (stable desc order == jax.lax.top_k)
    if (tid < n_per) {
        const float si = sc[tid];
        int rank = 0;
        for (int j = 0; j < n_per; ++j) {
            float sj = sc[j];
            rank += (sj > si) || (sj == si && j < tid);
        }
        if (rank < k) {
            ord[rank] = tid;
            tf[rank] = tanhf(si);
            newid[nbase + tid] = g * k + rank;
        } else {
            newid[nbase + tid] = -1;
        }
    }
    __syncthreads();

    // gather + fused [max || mean] readout. f = tid&127 fixed per thread.
    const int f = tid & 127;
    const int grp = tid >> 7;    // 0..3
    float mx = -INFINITY, sm = 0.f;
    for (int t = tid; t < k * FD; t += 512) {
        int r = t >> 7;
        float val = h[(long)(nbase + ord[r]) * FD + f] * tf[r];
        xp[((long)g * k + r) * FD + f] = val;
        mx = fmaxf(mx, val);
        sm += val;
    }
    mxs[grp * 128 + f] = mx;
    sms[grp * 128 + f] = sm;
    __syncthreads();
    if (tid < 128) {
        float m0 = fmaxf(fmaxf(mxs[f], mxs[128 + f]), fmaxf(mxs[256 + f], mxs[384 + f]));
        float s0 = sms[f] + sms[128 + f] + sms[256 + f] + sms[384 + f];
        rout[g * 256 + f] = m0;
        rout[g * 256 + 128 + f] = s0 / (float)k;
    }
}

// ---------------- edge relabel + mask ------------------------------------------
__global__ __launch_bounds__(256) void relabel_kernel(const int* __restrict__ src,
                                                      const int* __restrict__ dst,
                                                      const float* __restrict__ ew,
                                                      const int* __restrict__ newid,
                                                      int* __restrict__ nsrc,
                                                      int* __restrict__ ndst,
                                                      float* __restrict__ new_ew) {
    const int e = blockIdx.x * 256 + threadIdx.x;
    int s = src[e], d = dst[e];
    float w = ew ? ew[e] : 1.0f;
    int ns = newid[s], nd = newid[d];
    bool keep = (ns >= 0) && (nd >= 0);
    nsrc[e] = ns > 0 ? ns : 0;
    ndst[e] = nd > 0 ? nd : 0;
    new_ew[e] = keep ? w : 0.f;
}

// ---------------- final MLP + log_softmax --------------------------------------
__global__ __launch_bounds__(128) void mlp_kernel(const float* __restrict__ r1,
                                                  const float* __restrict__ r2,
                                                  const float* __restrict__ r3,
                                                  const float* __restrict__ L1,
                                                  const float* __restrict__ bl1,
                                                  const float* __restrict__ L2,
                                                  const float* __restrict__ bl2,
                                                  const float* __restrict__ L3,
                                                  const float* __restrict__ bl3,
                                                  float* __restrict__ out) {
    __shared__ float z[256], z1[128], z2[64];
    const int g = blockIdx.x, tid = threadIdx.x;
    for (int t = tid; t < 256; t += 128)
        z[t] = r1[g * 256 + t] + r2[g * 256 + t] + r3[g * 256 + t];
    __syncthreads();
    {
        float a = bl1[tid];
        for (int i = 0; i < 256; ++i) a += z[i] * L1[i * 128 + tid];
        z1[tid] = fmaxf(a, 0.f);
    }
    __syncthreads();
    if (tid < 64) {
        float a = bl2[tid];
        for (int i = 0; i < 128; ++i) a += z1[i] * L2[i * 64 + tid];
        z2[tid] = fmaxf(a, 0.f);
    }
    __syncthreads();
    if (tid == 0) {
        float l0 = bl3[0], l1v = bl3[1];
        for (int i = 0; i < 64; ++i) {
            l0  += z2[i] * L3[i * 2 + 0];
            l1v += z2[i] * L3[i * 2 + 1];
        }
        float m = fmaxf(l0, l1v);
        float lse = m + logf(expf(l0 - m) + expf(l1v - m));
        out[g * 2 + 0] = l0 - lse;
        out[g * 2 + 1] = l1v - lse;
    }
}

extern "C" void kernel_launch(void* const* d_in, const int* in_sizes, int n_in,
                              void* d_out, int out_size, void* d_ws, size_t ws_size,
                              hipStream_t stream) {
    const float* x   = (const float*)d_in[0];
    const int*  src0 = (const int*)d_in[1];
    const int*  dst0 = (const int*)d_in[2];
    const float* W1 = (const float*)d_in[3];  const float* b1  = (const float*)d_in[4];
    const float* W2 = (const float*)d_in[5];  const float* b2  = (const float*)d_in[6];
    const float* W3 = (const float*)d_in[7];  const float* b3  = (const float*)d_in[8];
    const float* p1 = (const float*)d_in[9];  const float* p2  = (const float*)d_in[10];
    const float* p3 = (const float*)d_in[11];
    const float* L1 = (const float*)d_in[12]; const float* bl1 = (const float*)d_in[13];
    const float* L2 = (const float*)d_in[14]; const float* bl2 = (const float*)d_in[15];
    const float* L3 = (const float*)d_in[16]; const float* bl3 = (const float*)d_in[17];
    float* out = (float*)d_out;

    char* wptr = (char*)d_ws;
    auto alloc = [&](size_t bytes) {
        char* r = wptr;
        wptr += (bytes + 255) & ~(size_t)255;
        return r;
    };
    float* hpre = (float*)alloc(65536ULL * FD * 4);
    float* hbuf = (float*)alloc(65536ULL * FD * 4);
    float* xp2  = (float*)alloc(32768ULL * FD * 4);
    float* xp3  = (float*)alloc(16384ULL * FD * 4);
    float* xp4  = (float*)alloc(8192ULL * FD * 4);
    float* dinv = (float*)alloc(65536ULL * 4);
    float* scraw= (float*)alloc(65536ULL * 4);
    int*   nid  = (int*)alloc(65536ULL * 4);
    int*   src1 = (int*)alloc(NE * 4);
    int*   dst1 = (int*)alloc(NE * 4);
    float* ew1  = (float*)alloc(NE * 4);
    int*   src2 = (int*)alloc(NE * 4);
    int*   dst2 = (int*)alloc(NE * 4);
    float* ew2  = (float*)alloc(NE * 4);
    int*   roff = (int*)alloc((size_t)NB * 513 * 4);
    float2* cpair = (float2*)alloc((size_t)NE * 8);
    float* r1   = (float*)alloc(128ULL * 256 * 4);
    float* r2   = (float*)alloc(128ULL * 256 * 4);
    float* r3   = (float*)alloc(128ULL * 256 * 4);

    // ---- stage 1 (n_per=512 -> k=256): 4 tiles/graph -> S=2 ----
    gemm128_v2<<<512, 256, 0, stream>>>(x, W1, hpre, 2);
    build_csr<<<NB, 256, 0, stream>>>(src0, dst0, nullptr, 512, dinv, roff, cpair);
    agg_csr<<<65536 / 2, 256, 0, stream>>>(hpre, roff, cpair, dinv, b1, p1, 9, hbuf, scraw);
    pool_kernel<<<NB, 512, 0, stream>>>(hbuf, scraw, p1, 512, 256, xp2, nid, r1);
    relabel_kernel<<<NE / 256, 256, 0, stream>>>(src0, dst0, nullptr, nid, src1, dst1, ew1);

    // ---- stage 2 (n_per=256 -> k=128): 2 tiles/graph -> S=1 ----
    gemm128_v2<<<256, 256, 0, stream>>>(xp2, W2, hpre, 1);
    build_csr<<<NB, 256, 0, stream>>>(src1, dst1, ew1, 256, dinv, roff, cpair);
    agg_csr<<<32768 / 2, 256, 0, stream>>>(hpre, roff, cpair, dinv, b2, p2, 8, hbuf, scraw);
    pool_kernel<<<NB, 512, 0, stream>>>(hbuf, scraw, p2, 256, 128, xp3, nid, r2);
    relabel_kernel<<<NE / 256, 256, 0, stream>>>(src1, dst1, ew1, nid, src2, dst2, ew2);

    // ---- stage 3 (n_per=128 -> k=64): 1 tile/graph -> S=0 ----
    gemm128_v2<<<128, 256, 0, stream>>>(xp3, W3, hpre, 0);
    build_csr<<<NB, 256, 0, stream>>>(src2, dst2, ew2, 128, dinv, roff, cpair);
    agg_csr<<<16384 / 2, 256, 0, stream>>>(hpre, roff, cpair, dinv, b3, p3, 7, hbuf, scraw);
    pool_kernel<<<NB, 512, 0, stream>>>(hbuf, scraw, p3, 128, 64, xp4, nid, r3);

    // ---- final MLP ----
    mlp_kernel<<<NB, 128, 0, stream>>>(r1, r2, r3, L1, bl1, L2, bl2, L3, bl3, out);
}

// Round 11
// 344.143 us; speedup vs baseline: 2.3984x; 1.1039x over previous
//
#include <hip/hip_runtime.h>
#include <math.h>

#define NB 128          // batch of graphs
#define E_PER 2048
#define NE (NB * E_PER) // 262144 edges
#define FD 128          // feature dim (F_IN = NHID)

// ---------------- GEMM: C[N x 128] = A[N x 128] @ W[128 x 128] (f32) ----------
// 64x128 tile / block, 256 threads, K chunked by 32. LDS ~25 KB.
// Tile swizzled so tile's graph lands on XCD (graph&7) == consumer kernels.
// S = log2(tiles per graph). orig = ((q>>S)<<(3+S)) | (xcd<<S) | (q&(2^S-1)).
__global__ __launch_bounds__(256) void gemm64(const float* __restrict__ A,
                                              const float* __restrict__ W,
                                              float* __restrict__ C,
                                              int swz_shift) {
    const int bid = blockIdx.x;
    const int xcd = bid & 7;
    const int q = bid >> 3;
    const int S = swz_shift;
    const int tile = ((q >> S) << (3 + S)) | (xcd << S) | (q & ((1 << S) - 1));

    __shared__ float At[32 * 68];    // [k][row], 64 rows padded to 68 (8.7 KB)
    __shared__ float Wt[32 * 128];   // [k][col] (16 KB)
    const int tid = threadIdx.x;
    const long rbase = (long)tile * 64;
    const int cg = tid & 15;         // col quad 0..15
    const int rg = tid >> 4;         // row quad 0..15 (64 rows)

    float acc[2][4][4];
#pragma unroll
    for (int b = 0; b < 2; ++b)
#pragma unroll
        for (int i = 0; i < 4; ++i)
#pragma unroll
            for (int j = 0; j < 4; ++j) acc[b][i][j] = 0.f;

    for (int k0 = 0; k0 < 128; k0 += 32) {
        __syncthreads();
#pragma unroll
        for (int qq = 0; qq < 2; ++qq) {
            int idx = tid + 256 * qq;         // 0..511
            int row = idx >> 3, kq = idx & 7; // coalesced: 8 rows x 128B
            float4 a = *(const float4*)&A[(rbase + row) * FD + k0 + kq * 4];
            At[(kq * 4 + 0) * 68 + row] = a.x;
            At[(kq * 4 + 1) * 68 + row] = a.y;
            At[(kq * 4 + 2) * 68 + row] = a.z;
            At[(kq * 4 + 3) * 68 + row] = a.w;
        }
#pragma unroll
        for (int qq = 0; qq < 4; ++qq) {
            int idx = tid + 256 * qq;
            int kk = idx >> 5, cq = idx & 31;
            *(float4*)&Wt[kk * 128 + cq * 4] =
                *(const float4*)&W[(k0 + kk) * FD + cq * 4];
        }
        __syncthreads();
#pragma unroll 8
        for (int kk = 0; kk < 32; ++kk) {
            float4 a  = *(const float4*)&At[kk * 68 + rg * 4];
            float4 b0 = *(const float4*)&Wt[kk * 128 + cg * 4];
            float4 b1 = *(const float4*)&Wt[kk * 128 + 64 + cg * 4];
            float av[4] = {a.x, a.y, a.z, a.w};
            float bv[2][4] = {{b0.x, b0.y, b0.z, b0.w}, {b1.x, b1.y, b1.z, b1.w}};
#pragma unroll
            for (int b = 0; b < 2; ++b)
#pragma unroll
                for (int i = 0; i < 4; ++i)
#pragma unroll
                    for (int j = 0; j < 4; ++j)
                        acc[b][i][j] += av[i] * bv[b][j];
        }
    }
#pragma unroll
    for (int i = 0; i < 4; ++i) {
        long row = rbase + rg * 4 + i;
#pragma unroll
        for (int b = 0; b < 2; ++b) {
            float4 o = {acc[b][i][0], acc[b][i][1], acc[b][i][2], acc[b][i][3]};
            *(float4*)&C[row * FD + b * 64 + cg * 4] = o;
        }
    }
}

// -------- build per-graph CSR by dst + dinv + edge (src,coef) pairs -----------
__global__ __launch_bounds__(256) void build_csr(const int* __restrict__ src,
                                                 const int* __restrict__ dst,
                                                 const float* __restrict__ ew,
                                                 int n_per,
                                                 float* __restrict__ dinv,
                                                 int* __restrict__ roff,
                                                 float2* __restrict__ cpair) {
    __shared__ int   cnt[512];
    __shared__ int   offs[513];
    __shared__ float dl[512];
    const int g = blockIdx.x, tid = threadIdx.x;
    const int ebase = g * E_PER;
    const int nbase = g * n_per;

    for (int i = tid; i < n_per; i += 256) cnt[i] = 0;
    __syncthreads();
    for (int i = tid; i < E_PER; i += 256) {
        float w = ew ? ew[ebase + i] : 1.0f;
        if (w != 0.f) atomicAdd(&cnt[dst[ebase + i] - nbase], 1);
    }
    __syncthreads();
    for (int i = tid; i < n_per; i += 256) {
        float di = rsqrtf(1.0f + (float)cnt[i]);
        dl[i] = di;
        dinv[nbase + i] = di;
    }
    // exclusive scan: serial on thread 0 (correct; cost negligible at 128 blocks)
    __syncthreads();
    if (tid == 0) {
        int run = 0;
        for (int i = 0; i < n_per; ++i) { offs[i] = run; run += cnt[i]; }
        offs[n_per] = run;
    }
    __syncthreads();
    for (int i = tid; i <= n_per; i += 256)
        roff[g * (n_per + 1) + i] = ebase + offs[i];
    for (int i = tid; i < n_per; i += 256) cnt[i] = offs[i];  // cursors
    __syncthreads();
    for (int i = tid; i < E_PER; i += 256) {
        float w = ew ? ew[ebase + i] : 1.0f;
        if (w != 0.f) {
            int s = src[ebase + i], d = dst[ebase + i];
            int dlo = d - nbase;
            int pos = atomicAdd(&cnt[dlo], 1);
            cpair[ebase + pos] = make_float2(__int_as_float(s), dl[s - nbase] * dl[dlo] * w);
        }
    }
}

// -------- aggregate via CSR gather + FUSED raw pool-score ---------------------
// ONE WAVE per node: 64 lanes x float2 (2 feats/lane). 4 nodes/block.
// No LDS, no barriers. XCD-pinned: graph g -> XCD (g&7).
__global__ __launch_bounds__(256) void agg_csr(const float* __restrict__ hpre,
                                               const int* __restrict__ roff,
                                               const float2* __restrict__ cpair,
                                               const float* __restrict__ dinv,
                                               const float* __restrict__ bias,
                                               const float* __restrict__ pvec,
                                               int np_shift,
                                               float* __restrict__ hout,
                                               float* __restrict__ scraw) {
    const int tid = threadIdx.x;
    const int P = 1 << (np_shift - 2);          // blocks per graph (4 nodes/block)
    const int xcd = blockIdx.x & 7;
    const int idx = blockIdx.x >> 3;
    const int p = idx & (P - 1);
    const int g = ((idx >> (np_shift - 2)) << 3) + xcd;
    const int n_per = 1 << np_shift;
    const int nl = p * 4 + (tid >> 6);          // wave id 0..3
    const int node = g * n_per + nl;
    const int l = tid & 63;                     // float2 lane: feats 2l, 2l+1
    const float2* __restrict__ hpre2 = (const float2*)hpre;
    const int rbase = g * (n_per + 1) + nl;
    const int e0 = roff[rbase], e1 = roff[rbase + 1];
    const float2 selfh = hpre2[(long)node * 64 + l];
    float ax = 0.f, ay = 0.f;
    int e = e0, n = e1 - e0;
    while (n >= 4) {
        float2 p0 = cpair[e], p1 = cpair[e + 1], p2 = cpair[e + 2], p3 = cpair[e + 3];
        float2 h0 = hpre2[(long)__float_as_int(p0.x) * 64 + l];
        float2 h1 = hpre2[(long)__float_as_int(p1.x) * 64 + l];
        float2 h2 = hpre2[(long)__float_as_int(p2.x) * 64 + l];
        float2 h3 = hpre2[(long)__float_as_int(p3.x) * 64 + l];
        ax += h0.x * p0.y + h1.x * p1.y + h2.x * p2.y + h3.x * p3.y;
        ay += h0.y * p0.y + h1.y * p1.y + h2.y * p2.y + h3.y * p3.y;
        e += 4; n -= 4;
    }
    while (n > 0) {
        float2 pr = cpair[e];
        float2 hv = hpre2[(long)__float_as_int(pr.x) * 64 + l];
        ax += hv.x * pr.y;
        ay += hv.y * pr.y;
        ++e; --n;
    }
    const float di = dinv[node];
    const float d2 = di * di;
    const float2 bb = ((const float2*)bias)[l];
    float v0 = fmaxf(ax + selfh.x * d2 + bb.x, 0.f);
    float v1 = fmaxf(ay + selfh.y * d2 + bb.y, 0.f);
    ((float2*)hout)[(long)node * 64 + l] = make_float2(v0, v1);

    // fused raw score: wave-reduce (v0*p[2l] + v1*p[2l+1]) over 64 lanes
    const float2 pv = ((const float2*)pvec)[l];
    float pr = v0 * pv.x + v1 * pv.y;
#pragma unroll
    for (int o = 32; o > 0; o >>= 1) pr += __shfl_down(pr, o);
    if (l == 0) scraw[node] = pr;
}

// ------- TopK pool: rank-select on precomputed scores, gather*tanh + readout --
__global__ __launch_bounds__(512) void pool_kernel(const float* __restrict__ h,
                                                   const float* __restrict__ scraw,
                                                   const float* __restrict__ p,
                                                   int n_per, int k,
                                                   float* __restrict__ xp,
                                                   int* __restrict__ newid,
                                                   float* __restrict__ rout) {
    __shared__ float sc[512];
    __shared__ int   ord[256];   // rank -> local node idx (k <= 256)
    __shared__ float tf[256];    // tanh(score) by rank
    __shared__ float red[128];
    __shared__ float mxs[512];
    __shared__ float sms[512];
    const int tid = threadIdx.x;
    const int g = blockIdx.x;
    const int nbase = g * n_per;

    if (tid < 128) { float pv = p[tid]; red[tid] = pv * pv; }
    __syncthreads();
    for (int s = 64; s > 0; s >>= 1) {
        if (tid < s) red[tid] += red[tid + s];
        __syncthreads();
    }
    const float invn = rsqrtf(red[0]);

    // scores: precomputed raw dots (coalesced 2KB read), scale by 1/||p||
    if (tid < n_per) sc[tid] = scraw[nbase + tid] * invn;
    __syncthreads();

    // rank + scatter (stable desc order == jax.lax.top_k)
    if (tid < n_per) {
        const float si = sc[tid];
        int rank = 0;
        for (int j = 0; j < n_per; ++j) {
            float sj = sc[j];
            rank += (sj > si) || (sj == si && j < tid);
        }
        if (rank < k) {
            ord[rank] = tid;
            tf[rank] = tanhf(si);
            newid[nbase + tid] = g * k + rank;
        } else {
            newid[nbase + tid] = -1;
        }
    }
    __syncthreads();

    // gather + fused [max || mean] readout. f = tid&127 fixed per thread.
    const int f = tid & 127;
    const int grp = tid >> 7;    // 0..3
    float mx = -INFINITY, sm = 0.f;
    for (int t = tid; t < k * FD; t += 512) {
        int r = t >> 7;
        float val = h[(long)(nbase + ord[r]) * FD + f] * tf[r];
        xp[((long)g * k + r) * FD + f] = val;
        mx = fmaxf(mx, val);
        sm += val;
    }
    mxs[grp * 128 + f] = mx;
    sms[grp * 128 + f] = sm;
    __syncthreads();
    if (tid < 128) {
        float m0 = fmaxf(fmaxf(mxs[f], mxs[128 + f]), fmaxf(mxs[256 + f], mxs[384 + f]));
        float s0 = sms[f] + sms[128 + f] + sms[256 + f] + sms[384 + f];
        rout[g * 256 + f] = m0;
        rout[g * 256 + 128 + f] = s0 / (float)k;
    }
}

// ---------------- edge relabel + mask ------------------------------------------
__global__ __launch_bounds__(256) void relabel_kernel(const int* __restrict__ src,
                                                      const int* __restrict__ dst,
                                                      const float* __restrict__ ew,
                                                      const int* __restrict__ newid,
                                                      int* __restrict__ nsrc,
                                                      int* __restrict__ ndst,
                                                      float* __restrict__ new_ew) {
    const int e = blockIdx.x * 256 + threadIdx.x;
    int s = src[e], d = dst[e];
    float w = ew ? ew[e] : 1.0f;
    int ns = newid[s], nd = newid[d];
    bool keep = (ns >= 0) && (nd >= 0);
    nsrc[e] = ns > 0 ? ns : 0;
    ndst[e] = nd > 0 ? nd : 0;
    new_ew[e] = keep ? w : 0.f;
}

// ---------------- final MLP + log_softmax --------------------------------------
__global__ __launch_bounds__(128) void mlp_kernel(const float* __restrict__ r1,
                                                  const float* __restrict__ r2,
                                                  const float* __restrict__ r3,
                                                  const float* __restrict__ L1,
                                                  const float* __restrict__ bl1,
                                                  const float* __restrict__ L2,
                                                  const float* __restrict__ bl2,
                                                  const float* __restrict__ L3,
                                                  const float* __restrict__ bl3,
                                                  float* __restrict__ out) {
    __shared__ float z[256], z1[128], z2[64];
    const int g = blockIdx.x, tid = threadIdx.x;
    for (int t = tid; t < 256; t += 128)
        z[t] = r1[g * 256 + t] + r2[g * 256 + t] + r3[g * 256 + t];
    __syncthreads();
    {
        float a = bl1[tid];
        for (int i = 0; i < 256; ++i) a += z[i] * L1[i * 128 + tid];
        z1[tid] = fmaxf(a, 0.f);
    }
    __syncthreads();
    if (tid < 64) {
        float a = bl2[tid];
        for (int i = 0; i < 128; ++i) a += z1[i] * L2[i * 64 + tid];
        z2[tid] = fmaxf(a, 0.f);
    }
    __syncthreads();
    if (tid == 0) {
        float l0 = bl3[0], l1v = bl3[1];
        for (int i = 0; i < 64; ++i) {
            l0  += z2[i] * L3[i * 2 + 0];
            l1v += z2[i] * L3[i * 2 + 1];
        }
        float m = fmaxf(l0, l1v);
        float lse = m + logf(expf(l0 - m) + expf(l1v - m));
        out[g * 2 + 0] = l0 - lse;
        out[g * 2 + 1] = l1v - lse;
    }
}

extern "C" void kernel_launch(void* const* d_in, const int* in_sizes, int n_in,
                              void* d_out, int out_size, void* d_ws, size_t ws_size,
                              hipStream_t stream) {
    const float* x   = (const float*)d_in[0];
    const int*  src0 = (const int*)d_in[1];
    const int*  dst0 = (const int*)d_in[2];
    const float* W1 = (const float*)d_in[3];  const float* b1  = (const float*)d_in[4];
    const float* W2 = (const float*)d_in[5];  const float* b2  = (const float*)d_in[6];
    const float* W3 = (const float*)d_in[7];  const float* b3  = (const float*)d_in[8];
    const float* p1 = (const float*)d_in[9];  const float* p2  = (const float*)d_in[10];
    const float* p3 = (const float*)d_in[11];
    const float* L1 = (const float*)d_in[12]; const float* bl1 = (const float*)d_in[13];
    const float* L2 = (const float*)d_in[14]; const float* bl2 = (const float*)d_in[15];
    const float* L3 = (const float*)d_in[16]; const float* bl3 = (const float*)d_in[17];
    float* out = (float*)d_out;

    char* wptr = (char*)d_ws;
    auto alloc = [&](size_t bytes) {
        char* r = wptr;
        wptr += (bytes + 255) & ~(size_t)255;
        return r;
    };
    float* hpre = (float*)alloc(65536ULL * FD * 4);
    float* hbuf = (float*)alloc(65536ULL * FD * 4);
    float* xp2  = (float*)alloc(32768ULL * FD * 4);
    float* xp3  = (float*)alloc(16384ULL * FD * 4);
    float* xp4  = (float*)alloc(8192ULL * FD * 4);
    float* dinv = (float*)alloc(65536ULL * 4);
    float* scraw= (float*)alloc(65536ULL * 4);
    int*   nid  = (int*)alloc(65536ULL * 4);
    int*   src1 = (int*)alloc(NE * 4);
    int*   dst1 = (int*)alloc(NE * 4);
    float* ew1  = (float*)alloc(NE * 4);
    int*   src2 = (int*)alloc(NE * 4);
    int*   dst2 = (int*)alloc(NE * 4);
    float* ew2  = (float*)alloc(NE * 4);
    int*   roff = (int*)alloc((size_t)NB * 513 * 4);
    float2* cpair = (float2*)alloc((size_t)NE * 8);
    float* r1   = (float*)alloc(128ULL * 256 * 4);
    float* r2   = (float*)alloc(128ULL * 256 * 4);
    float* r3   = (float*)alloc(128ULL * 256 * 4);

    // ---- stage 1 (n_per=512 -> k=256): 8x64-row tiles/graph -> S=3 ----
    gemm64<<<1024, 256, 0, stream>>>(x, W1, hpre, 3);
    build_csr<<<NB, 256, 0, stream>>>(src0, dst0, nullptr, 512, dinv, roff, cpair);
    agg_csr<<<65536 / 4, 256, 0, stream>>>(hpre, roff, cpair, dinv, b1, p1, 9, hbuf, scraw);
    pool_kernel<<<NB, 512, 0, stream>>>(hbuf, scraw, p1, 512, 256, xp2, nid, r1);
    relabel_kernel<<<NE / 256, 256, 0, stream>>>(src0, dst0, nullptr, nid, src1, dst1, ew1);

    // ---- stage 2 (n_per=256 -> k=128): 4 tiles/graph -> S=2 ----
    gemm64<<<512, 256, 0, stream>>>(xp2, W2, hpre, 2);
    build_csr<<<NB, 256, 0, stream>>>(src1, dst1, ew1, 256, dinv, roff, cpair);
    agg_csr<<<32768 / 4, 256, 0, stream>>>(hpre, roff, cpair, dinv, b2, p2, 8, hbuf, scraw);
    pool_kernel<<<NB, 512, 0, stream>>>(hbuf, scraw, p2, 256, 128, xp3, nid, r2);
    relabel_kernel<<<NE / 256, 256, 0, stream>>>(src1, dst1, ew1, nid, src2, dst2, ew2);

    // ---- stage 3 (n_per=128 -> k=64): 2 tiles/graph -> S=1 ----
    gemm64<<<256, 256, 0, stream>>>(xp3, W3, hpre, 1);
    build_csr<<<NB, 256, 0, stream>>>(src2, dst2, ew2, 128, dinv, roff, cpair);
    agg_csr<<<16384 / 4, 256, 0, stream>>>(hpre, roff, cpair, dinv, b3, p3, 7, hbuf, scraw);
    pool_kernel<<<NB, 512, 0, stream>>>(hbuf, scraw, p3, 128, 64, xp4, nid, r3);

    // ---- final MLP ----
    mlp_kernel<<<NB, 128, 0, stream>>>(r1, r2, r3, L1, bl1, L2, bl2, L3, bl3, out);
}

// Round 12
// 331.153 us; speedup vs baseline: 2.4924x; 1.0392x over previous
//
#include <hip/hip_runtime.h>
#include <math.h>

#define NB 128          // batch of graphs
#define E_PER 2048
#define NE (NB * E_PER) // 262144 edges
#define FD 128          // feature dim (F_IN = NHID)

// ---------------- GEMM: C[N x 128] = A[N x 128] @ W[128 x 128] (f32) ----------
// 64x128 tile / block, 256 threads, K chunked by 32. LDS ~25 KB.
// Tile swizzled so tile's graph lands on XCD (graph&7) == consumer kernels.
__global__ __launch_bounds__(256) void gemm64(const float* __restrict__ A,
                                              const float* __restrict__ W,
                                              float* __restrict__ C,
                                              int swz_shift) {
    const int bid = blockIdx.x;
    const int xcd = bid & 7;
    const int q = bid >> 3;
    const int S = swz_shift;
    const int tile = ((q >> S) << (3 + S)) | (xcd << S) | (q & ((1 << S) - 1));

    __shared__ float At[32 * 68];    // [k][row], 64 rows padded to 68 (8.7 KB)
    __shared__ float Wt[32 * 128];   // [k][col] (16 KB)
    const int tid = threadIdx.x;
    const long rbase = (long)tile * 64;
    const int cg = tid & 15;         // col quad 0..15
    const int rg = tid >> 4;         // row quad 0..15 (64 rows)

    float acc[2][4][4];
#pragma unroll
    for (int b = 0; b < 2; ++b)
#pragma unroll
        for (int i = 0; i < 4; ++i)
#pragma unroll
            for (int j = 0; j < 4; ++j) acc[b][i][j] = 0.f;

    for (int k0 = 0; k0 < 128; k0 += 32) {
        __syncthreads();
#pragma unroll
        for (int qq = 0; qq < 2; ++qq) {
            int idx = tid + 256 * qq;         // 0..511
            int row = idx >> 3, kq = idx & 7; // coalesced: 8 rows x 128B
            float4 a = *(const float4*)&A[(rbase + row) * FD + k0 + kq * 4];
            At[(kq * 4 + 0) * 68 + row] = a.x;
            At[(kq * 4 + 1) * 68 + row] = a.y;
            At[(kq * 4 + 2) * 68 + row] = a.z;
            At[(kq * 4 + 3) * 68 + row] = a.w;
        }
#pragma unroll
        for (int qq = 0; qq < 4; ++qq) {
            int idx = tid + 256 * qq;
            int kk = idx >> 5, cq = idx & 31;
            *(float4*)&Wt[kk * 128 + cq * 4] =
                *(const float4*)&W[(k0 + kk) * FD + cq * 4];
        }
        __syncthreads();
#pragma unroll 8
        for (int kk = 0; kk < 32; ++kk) {
            float4 a  = *(const float4*)&At[kk * 68 + rg * 4];
            float4 b0 = *(const float4*)&Wt[kk * 128 + cg * 4];
            float4 b1 = *(const float4*)&Wt[kk * 128 + 64 + cg * 4];
            float av[4] = {a.x, a.y, a.z, a.w};
            float bv[2][4] = {{b0.x, b0.y, b0.z, b0.w}, {b1.x, b1.y, b1.z, b1.w}};
#pragma unroll
            for (int b = 0; b < 2; ++b)
#pragma unroll
                for (int i = 0; i < 4; ++i)
#pragma unroll
                    for (int j = 0; j < 4; ++j)
                        acc[b][i][j] += av[i] * bv[b][j];
        }
    }
#pragma unroll
    for (int i = 0; i < 4; ++i) {
        long row = rbase + rg * 4 + i;
#pragma unroll
        for (int b = 0; b < 2; ++b) {
            float4 o = {acc[b][i][0], acc[b][i][1], acc[b][i][2], acc[b][i][3]};
            *(float4*)&C[row * FD + b * 64 + cg * 4] = o;
        }
    }
}

// ---- build per-graph CSR by dst + dinv + edge (src,coef), FUSED relabel ------
// Reads ORIGINAL src0/dst0; endpoint id = map2[map1[v]] (each level optional).
// Edge survives iff both endpoints >= 0 at every level (== ew*keep chain).
__global__ __launch_bounds__(256) void build_csr(const int* __restrict__ src,
                                                 const int* __restrict__ dst,
                                                 const int* __restrict__ map1,
                                                 const int* __restrict__ map2,
                                                 int n_per,
                                                 float* __restrict__ dinv,
                                                 int* __restrict__ roff,
                                                 float2* __restrict__ cpair) {
    __shared__ int   cnt[512];
    __shared__ int   offs[513];
    __shared__ float dl[512];
    const int g = blockIdx.x, tid = threadIdx.x;
    const int ebase = g * E_PER;
    const int nbase = g * n_per;

    auto mapid = [&](int v) -> int {
        if (map1) { v = map1[v]; if (v < 0) return -1; }
        if (map2) { v = map2[v]; }
        return v;
    };

    for (int i = tid; i < n_per; i += 256) cnt[i] = 0;
    __syncthreads();
    for (int i = tid; i < E_PER; i += 256) {
        int ms = mapid(src[ebase + i]);
        int md = mapid(dst[ebase + i]);
        if (ms >= 0 && md >= 0) atomicAdd(&cnt[md - nbase], 1);
    }
    __syncthreads();
    for (int i = tid; i < n_per; i += 256) {
        float di = rsqrtf(1.0f + (float)cnt[i]);
        dl[i] = di;
        dinv[nbase + i] = di;
    }
    // exclusive scan: serial on thread 0 (correct; cost negligible at 128 blocks)
    __syncthreads();
    if (tid == 0) {
        int run = 0;
        for (int i = 0; i < n_per; ++i) { offs[i] = run; run += cnt[i]; }
        offs[n_per] = run;
    }
    __syncthreads();
    for (int i = tid; i <= n_per; i += 256)
        roff[g * (n_per + 1) + i] = ebase + offs[i];
    for (int i = tid; i < n_per; i += 256) cnt[i] = offs[i];  // cursors
    __syncthreads();
    for (int i = tid; i < E_PER; i += 256) {
        int ms = mapid(src[ebase + i]);
        int md = mapid(dst[ebase + i]);
        if (ms >= 0 && md >= 0) {
            int dlo = md - nbase;
            int pos = atomicAdd(&cnt[dlo], 1);
            cpair[ebase + pos] = make_float2(__int_as_float(ms), dl[ms - nbase] * dl[dlo]);
        }
    }
}

// -------- aggregate via CSR gather + FUSED raw pool-score ---------------------
// ONE WAVE per node: 64 lanes x float2 (2 feats/lane). 4 nodes/block.
// No LDS, no barriers. XCD-pinned: graph g -> XCD (g&7).
__global__ __launch_bounds__(256) void agg_csr(const float* __restrict__ hpre,
                                               const int* __restrict__ roff,
                                               const float2* __restrict__ cpair,
                                               const float* __restrict__ dinv,
                                               const float* __restrict__ bias,
                                               const float* __restrict__ pvec,
                                               int np_shift,
                                               float* __restrict__ hout,
                                               float* __restrict__ scraw) {
    const int tid = threadIdx.x;
    const int P = 1 << (np_shift - 2);          // blocks per graph (4 nodes/block)
    const int xcd = blockIdx.x & 7;
    const int idx = blockIdx.x >> 3;
    const int p = idx & (P - 1);
    const int g = ((idx >> (np_shift - 2)) << 3) + xcd;
    const int n_per = 1 << np_shift;
    const int nl = p * 4 + (tid >> 6);          // wave id 0..3
    const int node = g * n_per + nl;
    const int l = tid & 63;                     // float2 lane: feats 2l, 2l+1
    const float2* __restrict__ hpre2 = (const float2*)hpre;
    const int rbase = g * (n_per + 1) + nl;
    const int e0 = roff[rbase], e1 = roff[rbase + 1];
    const float2 selfh = hpre2[(long)node * 64 + l];
    float ax = 0.f, ay = 0.f;
    int e = e0, n = e1 - e0;
    while (n >= 4) {
        float2 p0 = cpair[e], p1 = cpair[e + 1], p2 = cpair[e + 2], p3 = cpair[e + 3];
        float2 h0 = hpre2[(long)__float_as_int(p0.x) * 64 + l];
        float2 h1 = hpre2[(long)__float_as_int(p1.x) * 64 + l];
        float2 h2 = hpre2[(long)__float_as_int(p2.x) * 64 + l];
        float2 h3 = hpre2[(long)__float_as_int(p3.x) * 64 + l];
        ax += h0.x * p0.y + h1.x * p1.y + h2.x * p2.y + h3.x * p3.y;
        ay += h0.y * p0.y + h1.y * p1.y + h2.y * p2.y + h3.y * p3.y;
        e += 4; n -= 4;
    }
    while (n > 0) {
        float2 pr = cpair[e];
        float2 hv = hpre2[(long)__float_as_int(pr.x) * 64 + l];
        ax += hv.x * pr.y;
        ay += hv.y * pr.y;
        ++e; --n;
    }
    const float di = dinv[node];
    const float d2 = di * di;
    const float2 bb = ((const float2*)bias)[l];
    float v0 = fmaxf(ax + selfh.x * d2 + bb.x, 0.f);
    float v1 = fmaxf(ay + selfh.y * d2 + bb.y, 0.f);
    ((float2*)hout)[(long)node * 64 + l] = make_float2(v0, v1);

    // fused raw score: wave-reduce (v0*p[2l] + v1*p[2l+1]) over 64 lanes
    const float2 pv = ((const float2*)pvec)[l];
    float pr = v0 * pv.x + v1 * pv.y;
#pragma unroll
    for (int o = 32; o > 0; o >>= 1) pr += __shfl_down(pr, o);
    if (l == 0) scraw[node] = pr;
}

// ------- TopK pool: rank-select on precomputed scores, gather*tanh + readout --
// 1024 threads (16 waves) to hide gather latency.
__global__ __launch_bounds__(1024) void pool_kernel(const float* __restrict__ h,
                                                    const float* __restrict__ scraw,
                                                    const float* __restrict__ p,
                                                    int n_per, int k,
                                                    float* __restrict__ xp,
                                                    int* __restrict__ newid,
                                                    float* __restrict__ rout) {
    __shared__ float sc[512];
    __shared__ int   ord[256];   // rank -> local node idx (k <= 256)
    __shared__ float tf[256];    // tanh(score) by rank
    __shared__ float red[128];
    __shared__ float mxs[1024];
    __shared__ float sms[1024];
    const int tid = threadIdx.x;
    const int g = blockIdx.x;
    const int nbase = g * n_per;

    if (tid < 128) { float pv = p[tid]; red[tid] = pv * pv; }
    __syncthreads();
    for (int s = 64; s > 0; s >>= 1) {
        if (tid < s) red[tid] += red[tid + s];
        __syncthreads();
    }
    const float invn = rsqrtf(red[0]);

    // scores: precomputed raw dots (coalesced 2KB read), scale by 1/||p||
    if (tid < n_per) sc[tid] = scraw[nbase + tid] * invn;
    __syncthreads();

    // rank + scatter (stable desc order == jax.lax.top_k)
    if (tid < n_per) {
        const float si = sc[tid];
        int rank = 0;
        for (int j = 0; j < n_per; ++j) {
            float sj = sc[j];
            rank += (sj > si) || (sj == si && j < tid);
        }
        if (rank < k) {
            ord[rank] = tid;
            tf[rank] = tanhf(si);
            newid[nbase + tid] = g * k + rank;
        } else {
            newid[nbase + tid] = -1;
        }
    }
    __syncthreads();

    // gather + fused [max || mean] readout. f = tid&127 fixed per thread.
    const int f = tid & 127;
    const int grp = tid >> 7;    // 0..7
    float mx = -INFINITY, sm = 0.f;
    for (int t = tid; t < k * FD; t += 1024) {
        int r = t >> 7;
        float val = h[(long)(nbase + ord[r]) * FD + f] * tf[r];
        xp[((long)g * k + r) * FD + f] = val;
        mx = fmaxf(mx, val);
        sm += val;
    }
    mxs[grp * 128 + f] = mx;
    sms[grp * 128 + f] = sm;
    __syncthreads();
    if (tid < 128) {
        float m0 = mxs[f], s0 = sms[f];
#pragma unroll
        for (int q = 1; q < 8; ++q) {
            m0 = fmaxf(m0, mxs[q * 128 + f]);
            s0 += sms[q * 128 + f];
        }
        rout[g * 256 + f] = m0;
        rout[g * 256 + 128 + f] = s0 / (float)k;
    }
}

// ---------------- final MLP + log_softmax --------------------------------------
__global__ __launch_bounds__(128) void mlp_kernel(const float* __restrict__ r1,
                                                  const float* __restrict__ r2,
                                                  const float* __restrict__ r3,
                                                  const float* __restrict__ L1,
                                                  const float* __restrict__ bl1,
                                                  const float* __restrict__ L2,
                                                  const float* __restrict__ bl2,
                                                  const float* __restrict__ L3,
                                                  const float* __restrict__ bl3,
                                                  float* __restrict__ out) {
    __shared__ float z[256], z1[128], z2[64];
    const int g = blockIdx.x, tid = threadIdx.x;
    for (int t = tid; t < 256; t += 128)
        z[t] = r1[g * 256 + t] + r2[g * 256 + t] + r3[g * 256 + t];
    __syncthreads();
    {
        float a = bl1[tid];
        for (int i = 0; i < 256; ++i) a += z[i] * L1[i * 128 + tid];
        z1[tid] = fmaxf(a, 0.f);
    }
    __syncthreads();
    if (tid < 64) {
        float a = bl2[tid];
        for (int i = 0; i < 128; ++i) a += z1[i] * L2[i * 64 + tid];
        z2[tid] = fmaxf(a, 0.f);
    }
    __syncthreads();
    if (tid == 0) {
        float l0 = bl3[0], l1v = bl3[1];
        for (int i = 0; i < 64; ++i) {
            l0  += z2[i] * L3[i * 2 + 0];
            l1v += z2[i] * L3[i * 2 + 1];
        }
        float m = fmaxf(l0, l1v);
        float lse = m + logf(expf(l0 - m) + expf(l1v - m));
        out[g * 2 + 0] = l0 - lse;
        out[g * 2 + 1] = l1v - lse;
    }
}

extern "C" void kernel_launch(void* const* d_in, const int* in_sizes, int n_in,
                              void* d_out, int out_size, void* d_ws, size_t ws_size,
                              hipStream_t stream) {
    const float* x   = (const float*)d_in[0];
    const int*  src0 = (const int*)d_in[1];
    const int*  dst0 = (const int*)d_in[2];
    const float* W1 = (const float*)d_in[3];  const float* b1  = (const float*)d_in[4];
    const float* W2 = (const float*)d_in[5];  const float* b2  = (const float*)d_in[6];
    const float* W3 = (const float*)d_in[7];  const float* b3  = (const float*)d_in[8];
    const float* p1 = (const float*)d_in[9];  const float* p2  = (const float*)d_in[10];
    const float* p3 = (const float*)d_in[11];
    const float* L1 = (const float*)d_in[12]; const float* bl1 = (const float*)d_in[13];
    const float* L2 = (const float*)d_in[14]; const float* bl2 = (const float*)d_in[15];
    const float* L3 = (const float*)d_in[16]; const float* bl3 = (const float*)d_in[17];
    float* out = (float*)d_out;

    char* wptr = (char*)d_ws;
    auto alloc = [&](size_t bytes) {
        char* r = wptr;
        wptr += (bytes + 255) & ~(size_t)255;
        return r;
    };
    float* hpre = (float*)alloc(65536ULL * FD * 4);
    float* hbuf = (float*)alloc(65536ULL * FD * 4);
    float* xp2  = (float*)alloc(32768ULL * FD * 4);
    float* xp3  = (float*)alloc(16384ULL * FD * 4);
    float* xp4  = (float*)alloc(8192ULL * FD * 4);
    float* dinv = (float*)alloc(65536ULL * 4);
    float* scraw= (float*)alloc(65536ULL * 4);
    int*   nid1 = (int*)alloc(65536ULL * 4);
    int*   nid2 = (int*)alloc(32768ULL * 4);
    int*   nid3 = (int*)alloc(16384ULL * 4);
    int*   roff = (int*)alloc((size_t)NB * 513 * 4);
    float2* cpair = (float2*)alloc((size_t)NE * 8);
    float* r1   = (float*)alloc(128ULL * 256 * 4);
    float* r2   = (float*)alloc(128ULL * 256 * 4);
    float* r3   = (float*)alloc(128ULL * 256 * 4);

    // ---- stage 1 (n_per=512 -> k=256): 8x64-row tiles/graph -> S=3 ----
    gemm64<<<1024, 256, 0, stream>>>(x, W1, hpre, 3);
    build_csr<<<NB, 256, 0, stream>>>(src0, dst0, nullptr, nullptr, 512, dinv, roff, cpair);
    agg_csr<<<65536 / 4, 256, 0, stream>>>(hpre, roff, cpair, dinv, b1, p1, 9, hbuf, scraw);
    pool_kernel<<<NB, 1024, 0, stream>>>(hbuf, scraw, p1, 512, 256, xp2, nid1, r1);

    // ---- stage 2 (n_per=256 -> k=128): 4 tiles/graph -> S=2 ----
    gemm64<<<512, 256, 0, stream>>>(xp2, W2, hpre, 2);
    build_csr<<<NB, 256, 0, stream>>>(src0, dst0, nid1, nullptr, 256, dinv, roff, cpair);
    agg_csr<<<32768 / 4, 256, 0, stream>>>(hpre, roff, cpair, dinv, b2, p2, 8, hbuf, scraw);
    pool_kernel<<<NB, 1024, 0, stream>>>(hbuf, scraw, p2, 256, 128, xp3, nid2, r2);

    // ---- stage 3 (n_per=128 -> k=64): 2 tiles/graph -> S=1 ----
    gemm64<<<256, 256, 0, stream>>>(xp3, W3, hpre, 1);
    build_csr<<<NB, 256, 0, stream>>>(src0, dst0, nid1, nid2, 128, dinv, roff, cpair);
    agg_csr<<<16384 / 4, 256, 0, stream>>>(hpre, roff, cpair, dinv, b3, p3, 7, hbuf, scraw);
    pool_kernel<<<NB, 1024, 0, stream>>>(hbuf, scraw, p3, 128, 64, xp4, nid3, r3);

    // ---- final MLP ----
    mlp_kernel<<<NB, 128, 0, stream>>>(r1, r2, r3, L1, bl1, L2, bl2, L3, bl3, out);
}

// Round 14
// 283.639 us; speedup vs baseline: 2.9100x; 1.1675x over previous
//
#include <hip/hip_runtime.h>
#include <math.h>

#define NB 128          // batch of graphs
#define E_PER 2048
#define NE (NB * E_PER) // 262144 edges
#define FD 128          // feature dim (F_IN = NHID)

// ------- GEMM 32x128 tile / 256 thr, K chunks of 32. LDS ~21KB -> ~7 blk/CU ---
// XCD swizzle: graph(tile) -> XCD (g&7). If bid >= ngemm: run stage-1 CSR build.
__global__ __launch_bounds__(256) void gemm32(const float* __restrict__ A,
                                              const float* __restrict__ W,
                                              float* __restrict__ C,
                                              int swz_shift, int ngemm,
                                              const int* __restrict__ src0,
                                              const int* __restrict__ dst0,
                                              float* __restrict__ dinv,
                                              int* __restrict__ roff,
                                              float2* __restrict__ cpair) {
    __shared__ float smem[5248];           // gemm: At[1152]+Wt[4096]; build: reuse
    const int tid = threadIdx.x;
    const int bid = blockIdx.x;

    if (bid >= ngemm) {
        // ---------- stage-1 CSR build (identity map), one block per graph ------
        int* cnt  = (int*)&smem[0];        // [512]
        int* offs = (int*)&smem[512];      // [513]
        float* dl = &smem[1025];           // [512]
        const int g = bid - ngemm;
        const int ebase = g * E_PER;
        const int nbase = g * 512;
        for (int i = tid; i < 512; i += 256) cnt[i] = 0;
        __syncthreads();
        for (int i = tid; i < E_PER; i += 256)
            atomicAdd(&cnt[dst0[ebase + i] - nbase], 1);
        __syncthreads();
        for (int i = tid; i < 512; i += 256) {
            float di = rsqrtf(1.0f + (float)cnt[i]);
            dl[i] = di;
            dinv[nbase + i] = di;
        }
        __syncthreads();
        if (tid == 0) {
            int run = 0;
            for (int i = 0; i < 512; ++i) { offs[i] = run; run += cnt[i]; }
            offs[512] = run;
        }
        __syncthreads();
        for (int i = tid; i <= 512; i += 256) roff[g * 513 + i] = ebase + offs[i];
        for (int i = tid; i < 512; i += 256) cnt[i] = offs[i];
        __syncthreads();
        for (int i = tid; i < E_PER; i += 256) {
            int s = src0[ebase + i] - nbase, d = dst0[ebase + i] - nbase;
            int pos = atomicAdd(&cnt[d], 1);
            cpair[ebase + pos] = make_float2(__int_as_float(nbase + s), dl[s] * dl[d]);
        }
        return;
    }

    // ---------- gemm body ----------
    float* At = &smem[0];      // [32k][36row] transposed, pad 36
    float* Wt = &smem[1152];   // [32k][128col]
    const int xcd = bid & 7;
    const int q = bid >> 3;
    const int S = swz_shift;
    const int tile = ((q >> S) << (3 + S)) | (xcd << S) | (q & ((1 << S) - 1));
    const long rbase = (long)tile * 32;
    const int cq = tid & 31, rg = tid >> 5;   // 32 col-quads x 8 row-quads

    float acc[4][4];
#pragma unroll
    for (int i = 0; i < 4; ++i)
#pragma unroll
        for (int j = 0; j < 4; ++j) acc[i][j] = 0.f;

    for (int k0 = 0; k0 < 128; k0 += 32) {
        __syncthreads();
        {
            int row = tid >> 3, kq = tid & 7;     // coalesced: 8 rows x 128B
            float4 a = *(const float4*)&A[(rbase + row) * FD + k0 + kq * 4];
            At[(kq * 4 + 0) * 36 + row] = a.x;
            At[(kq * 4 + 1) * 36 + row] = a.y;
            At[(kq * 4 + 2) * 36 + row] = a.z;
            At[(kq * 4 + 3) * 36 + row] = a.w;
        }
#pragma unroll
        for (int qq = 0; qq < 4; ++qq) {
            int idx = tid + 256 * qq;
            int kk = idx >> 5, c4 = idx & 31;
            *(float4*)&Wt[kk * 128 + c4 * 4] =
                *(const float4*)&W[(k0 + kk) * FD + c4 * 4];
        }
        __syncthreads();
#pragma unroll 4
        for (int kk = 0; kk < 32; ++kk) {
            float4 a = *(const float4*)&At[kk * 36 + rg * 4];   // 2 addrs/wave: bcast
            float4 b = *(const float4*)&Wt[kk * 128 + cq * 4];  // 32 seq quads
            float av[4] = {a.x, a.y, a.z, a.w};
            float bv[4] = {b.x, b.y, b.z, b.w};
#pragma unroll
            for (int i = 0; i < 4; ++i)
#pragma unroll
                for (int j = 0; j < 4; ++j) acc[i][j] += av[i] * bv[j];
        }
    }
#pragma unroll
    for (int i = 0; i < 4; ++i) {
        float4 o = {acc[i][0], acc[i][1], acc[i][2], acc[i][3]};
        *(float4*)&C[(rbase + rg * 4 + i) * FD + cq * 4] = o;
    }
}

// -------- aggregate via CSR gather + FUSED raw pool-score ---------------------
// ONE WAVE per node: 64 lanes x float2. 4 nodes/block. XCD-pinned (g&7).
__global__ __launch_bounds__(256) void agg_csr(const float* __restrict__ hpre,
                                               const int* __restrict__ roff,
                                               const float2* __restrict__ cpair,
                                               const float* __restrict__ dinv,
                                               const float* __restrict__ bias,
                                               const float* __restrict__ pvec,
                                               int np_shift,
                                               float* __restrict__ hout,
                                               float* __restrict__ scraw) {
    const int tid = threadIdx.x;
    const int P = 1 << (np_shift - 2);
    const int xcd = blockIdx.x & 7;
    const int idx = blockIdx.x >> 3;
    const int p = idx & (P - 1);
    const int g = ((idx >> (np_shift - 2)) << 3) + xcd;
    const int n_per = 1 << np_shift;
    const int nl = p * 4 + (tid >> 6);
    const int node = g * n_per + nl;
    const int l = tid & 63;
    const float2* __restrict__ hpre2 = (const float2*)hpre;
    const int rbase = g * (n_per + 1) + nl;
    const int e0 = roff[rbase], e1 = roff[rbase + 1];
    const float2 selfh = hpre2[(long)node * 64 + l];
    float ax = 0.f, ay = 0.f;
    int e = e0, n = e1 - e0;
    while (n >= 4) {
        float2 p0 = cpair[e], p1 = cpair[e + 1], p2 = cpair[e + 2], p3 = cpair[e + 3];
        float2 h0 = hpre2[(long)__float_as_int(p0.x) * 64 + l];
        float2 h1 = hpre2[(long)__float_as_int(p1.x) * 64 + l];
        float2 h2 = hpre2[(long)__float_as_int(p2.x) * 64 + l];
        float2 h3 = hpre2[(long)__float_as_int(p3.x) * 64 + l];
        ax += h0.x * p0.y + h1.x * p1.y + h2.x * p2.y + h3.x * p3.y;
        ay += h0.y * p0.y + h1.y * p1.y + h2.y * p2.y + h3.y * p3.y;
        e += 4; n -= 4;
    }
    while (n > 0) {
        float2 pr = cpair[e];
        float2 hv = hpre2[(long)__float_as_int(pr.x) * 64 + l];
        ax += hv.x * pr.y;
        ay += hv.y * pr.y;
        ++e; --n;
    }
    const float di = dinv[node];
    const float d2 = di * di;
    const float2 bb = ((const float2*)bias)[l];
    float v0 = fmaxf(ax + selfh.x * d2 + bb.x, 0.f);
    float v1 = fmaxf(ay + selfh.y * d2 + bb.y, 0.f);
    ((float2*)hout)[(long)node * 64 + l] = make_float2(v0, v1);

    const float2 pv = ((const float2*)pvec)[l];
    float pr = v0 * pv.x + v1 * pv.y;
#pragma unroll
    for (int o = 32; o > 0; o >>= 1) pr += __shfl_down(pr, o);
    if (l == 0) scraw[node] = pr;
}

// ---- TopK pool (rank-select) + readout, FUSED next-stage CSR build / MLP -----
// STAGE 1: n=512,k=256: writes xp2, nid1, r1; builds stage-2 CSR (local map).
// STAGE 2: n=256,k=128: writes xp3, r2; builds stage-3 CSR (nid1 chain).
// STAGE 3: n=128,k=64 : no xp/nid; readout + z=r1+r2+r3 -> MLP -> out.
template<int STAGE>
__global__ __launch_bounds__(1024) void pool_fused(
    const float* __restrict__ h, const float* __restrict__ scraw,
    const float* __restrict__ p,
    float* __restrict__ xp, int* __restrict__ nid1, float* __restrict__ rout,
    const int* __restrict__ src0, const int* __restrict__ dst0,
    float* __restrict__ dinv, int* __restrict__ roff, float2* __restrict__ cpair,
    const float* __restrict__ r1, const float* __restrict__ r2,
    const float* __restrict__ L1, const float* __restrict__ bl1,
    const float* __restrict__ L2, const float* __restrict__ bl2,
    const float* __restrict__ L3, const float* __restrict__ bl3,
    float* __restrict__ out) {
    constexpr int n_per = (STAGE == 1) ? 512 : (STAGE == 2) ? 256 : 128;
    constexpr int k = n_per / 2;
    constexpr int n_next = k;
    __shared__ float sc[512];
    __shared__ int   ord[256];
    __shared__ float tf[256];
    __shared__ float red[128];
    __shared__ float mxs[1024];
    __shared__ float sms[1024];
    __shared__ int   nidl[512];    // current-stage node -> local rank (or -1)
    __shared__ int   cnt[256];
    __shared__ int   offs[257];
    __shared__ float dl2[256];
    __shared__ int   nid1l[512];   // STAGE==2: orig node -> stage-2 local id
    __shared__ float z[256], z1[128], z2[64];

    const int tid = threadIdx.x;
    const int g = blockIdx.x;
    const int nbase = g * n_per;

    if (tid < 128) { float pv = p[tid]; red[tid] = pv * pv; }
    __syncthreads();
    for (int s = 64; s > 0; s >>= 1) {
        if (tid < s) red[tid] += red[tid + s];
        __syncthreads();
    }
    const float invn = rsqrtf(red[0]);

    if (tid < n_per) sc[tid] = scraw[nbase + tid] * invn;
    __syncthreads();

    if (tid < n_per) {
        const float si = sc[tid];
        int rank = 0;
        for (int j = 0; j < n_per; ++j) {
            float sj = sc[j];
            rank += (sj > si) || (sj == si && j < tid);
        }
        if (rank < k) { ord[rank] = tid; tf[rank] = tanhf(si); nidl[tid] = rank; }
        else nidl[tid] = -1;
        if (STAGE == 1) nid1[nbase + tid] = (nidl[tid] < 0) ? -1 : g * k + nidl[tid];
    }
    __syncthreads();

    // gather + [max || mean] readout; f fixed per thread
    const int f = tid & 127;
    const int grp = tid >> 7;    // 0..7
    float mx = -INFINITY, sm = 0.f;
    for (int t = tid; t < k * FD; t += 1024) {
        int r = t >> 7;
        float val = h[(long)(nbase + ord[r]) * FD + f] * tf[r];
        if (STAGE < 3) xp[((long)g * k + r) * FD + f] = val;
        mx = fmaxf(mx, val);
        sm += val;
    }
    mxs[grp * 128 + f] = mx;
    sms[grp * 128 + f] = sm;
    __syncthreads();
    float m0 = 0.f, s0 = 0.f;
    if (tid < 128) {
        m0 = mxs[f]; s0 = sms[f];
#pragma unroll
        for (int qq = 1; qq < 8; ++qq) {
            m0 = fmaxf(m0, mxs[qq * 128 + f]);
            s0 += sms[qq * 128 + f];
        }
        if (STAGE < 3) {
            rout[g * 256 + f] = m0;
            rout[g * 256 + 128 + f] = s0 / (float)k;
        }
    }

    if constexpr (STAGE < 3) {
        // ---------- build next-stage CSR (all per-graph local) ----------
        if (STAGE == 2) {
            for (int i = tid; i < 512; i += 1024) {
                int v = nid1[g * 512 + i];
                nid1l[i] = (v < 0) ? -1 : (v - g * 256);
            }
        }
        for (int i = tid; i < n_next; i += 1024) cnt[i] = 0;
        __syncthreads();
        const int ebase = g * E_PER;
        auto edge_map = [&](int orig) -> int {
            int v = orig - g * 512;            // src0/dst0 hold original ids
            if (STAGE == 1) return nidl[v];
            int m = nid1l[v];
            return (m < 0) ? -1 : nidl[m];
        };
        for (int i = tid; i < E_PER; i += 1024) {
            int ms = edge_map(src0[ebase + i]);
            int md = edge_map(dst0[ebase + i]);
            if (ms >= 0 && md >= 0) atomicAdd(&cnt[md], 1);
        }
        __syncthreads();
        for (int i = tid; i < n_next; i += 1024) {
            float di = rsqrtf(1.0f + (float)cnt[i]);
            dl2[i] = di;
            dinv[g * n_next + i] = di;
        }
        __syncthreads();
        if (tid == 0) {
            int run = 0;
            for (int i = 0; i < n_next; ++i) { offs[i] = run; run += cnt[i]; }
            offs[n_next] = run;
        }
        __syncthreads();
        for (int i = tid; i <= n_next; i += 1024)
            roff[g * (n_next + 1) + i] = ebase + offs[i];
        for (int i = tid; i < n_next; i += 1024) cnt[i] = offs[i];
        __syncthreads();
        for (int i = tid; i < E_PER; i += 1024) {
            int ms = edge_map(src0[ebase + i]);
            int md = edge_map(dst0[ebase + i]);
            if (ms >= 0 && md >= 0) {
                int pos = atomicAdd(&cnt[md], 1);
                cpair[ebase + pos] =
                    make_float2(__int_as_float(g * n_next + ms), dl2[ms] * dl2[md]);
            }
        }
    } else {
        // ---------- fused final MLP + log_softmax ----------
        if (tid < 128) {
            z[f]       = r1[g * 256 + f]       + r2[g * 256 + f]       + m0;
            z[128 + f] = r1[g * 256 + 128 + f] + r2[g * 256 + 128 + f] + s0 / (float)k;
        }
        __syncthreads();
        if (tid < 128) {
            float a = bl1[tid];
            for (int i = 0; i < 256; ++i) a += z[i] * L1[i * 128 + tid];
            z1[tid] = fmaxf(a, 0.f);
        }
        __syncthreads();
        if (tid < 64) {
            float a = bl2[tid];
            for (int i = 0; i < 128; ++i) a += z1[i] * L2[i * 64 + tid];
            z2[tid] = fmaxf(a, 0.f);
        }
        __syncthreads();
        if (tid == 0) {
            float l0 = bl3[0], l1v = bl3[1];
            for (int i = 0; i < 64; ++i) {
                l0  += z2[i] * L3[i * 2 + 0];
                l1v += z2[i] * L3[i * 2 + 1];
            }
            float m = fmaxf(l0, l1v);
            float lse = m + logf(expf(l0 - m) + expf(l1v - m));
            out[g * 2 + 0] = l0 - lse;
            out[g * 2 + 1] = l1v - lse;
        }
    }
}

extern "C" void kernel_launch(void* const* d_in, const int* in_sizes, int n_in,
                              void* d_out, int out_size, void* d_ws, size_t ws_size,
                              hipStream_t stream) {
    const float* x   = (const float*)d_in[0];
    const int*  src0 = (const int*)d_in[1];
    const int*  dst0 = (const int*)d_in[2];
    const float* W1 = (const float*)d_in[3];  const float* b1  = (const float*)d_in[4];
    const float* W2 = (const float*)d_in[5];  const float* b2  = (const float*)d_in[6];
    const float* W3 = (const float*)d_in[7];  const float* b3  = (const float*)d_in[8];
    const float* p1 = (const float*)d_in[9];  const float* p2  = (const float*)d_in[10];
    const float* p3 = (const float*)d_in[11];
    const float* L1 = (const float*)d_in[12]; const float* bl1 = (const float*)d_in[13];
    const float* L2 = (const float*)d_in[14]; const float* bl2 = (const float*)d_in[15];
    const float* L3 = (const float*)d_in[16]; const float* bl3 = (const float*)d_in[17];
    float* out = (float*)d_out;

    char* wptr = (char*)d_ws;
    auto alloc = [&](size_t bytes) {
        char* r = wptr;
        wptr += (bytes + 255) & ~(size_t)255;
        return r;
    };
    float* hpre = (float*)alloc(65536ULL * FD * 4);
    float* hbuf = (float*)alloc(65536ULL * FD * 4);
    float* xp2  = (float*)alloc(32768ULL * FD * 4);
    float* xp3  = (float*)alloc(16384ULL * FD * 4);
    float* dinv = (float*)alloc(65536ULL * 4);
    float* scraw= (float*)alloc(65536ULL * 4);
    int*   nid1 = (int*)alloc(65536ULL * 4);
    int*   roff = (int*)alloc((size_t)NB * 513 * 4);
    float2* cpair = (float2*)alloc((size_t)NE * 8);
    float* r1   = (float*)alloc(128ULL * 256 * 4);
    float* r2   = (float*)alloc(128ULL * 256 * 4);

    // ---- stage 1 (512 -> 256): 16 tiles/graph S=4; +128 build-CSR blocks ----
    gemm32<<<2048 + NB, 256, 0, stream>>>(x, W1, hpre, 4, 2048,
                                          src0, dst0, dinv, roff, cpair);
    agg_csr<<<65536 / 4, 256, 0, stream>>>(hpre, roff, cpair, dinv, b1, p1, 9, hbuf, scraw);
    pool_fused<1><<<NB, 1024, 0, stream>>>(hbuf, scraw, p1, xp2, nid1, r1,
                                           src0, dst0, dinv, roff, cpair,
                                           nullptr, nullptr, nullptr, nullptr,
                                           nullptr, nullptr, nullptr, nullptr, nullptr);

    // ---- stage 2 (256 -> 128): 8 tiles/graph S=3 ----
    gemm32<<<1024, 256, 0, stream>>>(xp2, W2, hpre, 3, 1024,
                                     src0, dst0, dinv, roff, cpair);
    agg_csr<<<32768 / 4, 256, 0, stream>>>(hpre, roff, cpair, dinv, b2, p2, 8, hbuf, scraw);
    pool_fused<2><<<NB, 1024, 0, stream>>>(hbuf, scraw, p2, xp3, nid1, r2,
                                           src0, dst0, dinv, roff, cpair,
                                           nullptr, nullptr, nullptr, nullptr,
                                           nullptr, nullptr, nullptr, nullptr, nullptr);

    // ---- stage 3 (128 -> 64): 4 tiles/graph S=2; pool fuses readout+MLP ----
    gemm32<<<512, 256, 0, stream>>>(xp3, W3, hpre, 2, 512,
                                    src0, dst0, dinv, roff, cpair);
    agg_csr<<<16384 / 4, 256, 0, stream>>>(hpre, roff, cpair, dinv, b3, p3, 7, hbuf, scraw);
    pool_fused<3><<<NB, 1024, 0, stream>>>(hbuf, scraw, p3, nullptr, nid1, nullptr,
                                           src0, dst0, dinv, roff, cpair,
                                           r1, r2, L1, bl1, L2, bl2, L3, bl3, out);
}